// Round 1
// baseline (10104.491 us; speedup 1.0000x reference)
//
#include <hip/hip_runtime.h>

#define NNODES 100000
#define NEDGES 1600000
#define NGRAPHS 128
#define HID 128
#define INF 4
#define NCLS 2

// ---------------- degree / dinv ----------------
__global__ void deg_kernel(const int* __restrict__ col, float* __restrict__ deg) {
    int e = blockIdx.x * blockDim.x + threadIdx.x;
    if (e < NEDGES) atomicAdd(&deg[col[e]], 1.0f);
}

__global__ void dinv_kernel(float* __restrict__ deg) {
    int i = blockIdx.x * blockDim.x + threadIdx.x;
    if (i < NNODES) {
        float d = deg[i];
        deg[i] = (d > 0.0f) ? rsqrtf(d) : 0.0f;   // deg>0 => deg>=1, max(deg,1)=deg
    }
}

// ---------------- layer-1 propagation (F=4), one thread per edge ----------------
__global__ void prop4(const int* __restrict__ row, const int* __restrict__ col,
                      const float* __restrict__ dinv,
                      const float* __restrict__ hin, float* __restrict__ hout) {
    int e = blockIdx.x * blockDim.x + threadIdx.x;
    if (e >= NEDGES) return;
    int r = row[e], c = col[e];
    float w = dinv[r] * dinv[c];
    float4 v = *(const float4*)(hin + r * 4);
    float* dst = hout + c * 4;
    atomicAdd(dst + 0, w * v.x);
    atomicAdd(dst + 1, w * v.y);
    atomicAdd(dst + 2, w * v.z);
    atomicAdd(dst + 3, w * v.w);
}

// ---------------- layer-2 propagation (F=128), 32 threads (half-wave) per edge ----------------
__global__ void prop128(const int* __restrict__ row, const int* __restrict__ col,
                        const float* __restrict__ dinv,
                        const float* __restrict__ hin, float* __restrict__ hout) {
    int t = blockIdx.x * blockDim.x + threadIdx.x;
    int e = t >> 5;
    int c4 = (t & 31) * 4;
    if (e >= NEDGES) return;
    int r = row[e], c = col[e];
    float w = dinv[r] * dinv[c];
    float4 v = *(const float4*)(hin + r * HID + c4);
    float* dst = hout + c * HID + c4;
    atomicAdd(dst + 0, w * v.x);
    atomicAdd(dst + 1, w * v.y);
    atomicAdd(dst + 2, w * v.z);
    atomicAdd(dst + 3, w * v.w);
}

// ---------------- layer-1 combine: out1 = relu(x@W1[0]+h1@W1[1]+h2@W1[2]+h3@W1[3]+b1) ----------------
// block = 128 threads (one per output feature), 4 nodes per block
__global__ void combine1(const float* __restrict__ x, const float* __restrict__ h1,
                         const float* __restrict__ h2, const float* __restrict__ h3,
                         const float* __restrict__ W1, const float* __restrict__ b1,
                         float* __restrict__ out1) {
    __shared__ float hs[4][16];
    int n0 = blockIdx.x * 4;
    int j = threadIdx.x;  // 0..127
    if (j < 64) {
        int n = j >> 4, v = j & 15, k = v >> 2, i = v & 3;
        const float* src = (k == 0) ? x : (k == 1) ? h1 : (k == 2) ? h2 : h3;
        hs[n][v] = src[(n0 + n) * 4 + i];
    }
    __syncthreads();
    float w[16];
#pragma unroll
    for (int v = 0; v < 16; v++) w[v] = W1[v * 128 + j];  // (k,i,j) flat: (k*4+i)*128+j
    float bb = b1[j];
#pragma unroll
    for (int n = 0; n < 4; n++) {
        float acc = bb;
#pragma unroll
        for (int v = 0; v < 16; v++) acc += hs[n][v] * w[v];
        out1[(n0 + n) * 128 + j] = fmaxf(acc, 0.0f);
    }
}

// ---------------- C (=|+=) A @ W, A:[N,128], W:[128,128]; 8 nodes/block, 128 threads ----------------
// In-place safe for OVERWRITE (ACC=0) even when C==A: block stages its own rows first.
template <int ACC>
__global__ void gemm128(const float* __restrict__ A, const float* __restrict__ W,
                        float* __restrict__ C) {
    __shared__ float As[8][HID];
    int n0 = blockIdx.x * 8;
    int j = threadIdx.x;
#pragma unroll
    for (int r = 0; r < 8; r++) As[r][j] = A[(n0 + r) * HID + j];
    __syncthreads();
    float acc[8];
#pragma unroll
    for (int r = 0; r < 8; r++) acc[r] = ACC ? C[(n0 + r) * HID + j] : 0.0f;
    for (int i = 0; i < HID; i += 4) {
        float w0 = W[(i + 0) * HID + j];
        float w1 = W[(i + 1) * HID + j];
        float w2 = W[(i + 2) * HID + j];
        float w3 = W[(i + 3) * HID + j];
#pragma unroll
        for (int r = 0; r < 8; r++) {
            float4 a = *(const float4*)&As[r][i];
            acc[r] += a.x * w0 + a.y * w1 + a.z * w2 + a.w * w3;
        }
    }
#pragma unroll
    for (int r = 0; r < 8; r++) C[(n0 + r) * HID + j] = acc[r];
}

// ---------------- pooling: sums[g][j] += relu(acc[n][j] + b2[j]); cnts[g] += 1 ----------------
__global__ void pool_kernel(const float* __restrict__ acc, const float* __restrict__ b2,
                            const int* __restrict__ batch,
                            float* __restrict__ sums, float* __restrict__ cnts) {
    int t = blockIdx.x * blockDim.x + threadIdx.x;
    if (t >= NNODES * HID) return;
    int n = t >> 7, j = t & 127;
    int g = batch[n];
    float v = fmaxf(acc[t] + b2[j], 0.0f);
    atomicAdd(&sums[g * HID + j], v);
    if (j == 0) atomicAdd(&cnts[g], 1.0f);
}

// ---------------- head: logits = pooled@Wlin + blin; softmax ----------------
__global__ void head_kernel(const float* __restrict__ sums, const float* __restrict__ cnts,
                            const float* __restrict__ Wlin, const float* __restrict__ blin,
                            float* __restrict__ out) {
    int g = threadIdx.x;
    if (g >= NGRAPHS) return;
    float cnt = fmaxf(cnts[g], 1.0f);
    float l0 = blin[0], l1 = blin[1];
    for (int i = 0; i < HID; i++) {
        float p = sums[g * HID + i] / cnt;
        l0 += p * Wlin[i * 2 + 0];
        l1 += p * Wlin[i * 2 + 1];
    }
    float m = fmaxf(l0, l1);
    float e0 = __expf(l0 - m), e1 = __expf(l1 - m);
    float s = e0 + e1;
    out[g * 2 + 0] = e0 / s;
    out[g * 2 + 1] = e1 / s;
}

// ---------------- workspace layout (floats) ----------------
#define OFF_DINV 0
#define OFF_H1   100352            // pad 100000 -> 100352 (x128)
#define OFF_H2   (OFF_H1 + 400000)
#define OFF_H3   (OFF_H2 + 400000)
#define OFF_OUT1 (OFF_H3 + 400000)
#define OFF_GA   (OFF_OUT1 + 12800000)
#define OFF_GB   (OFF_GA + 12800000)
#define OFF_SUMS (OFF_GB + 12800000)
#define OFF_CNTS (OFF_SUMS + 16384)
#define WS_FLOATS (OFF_CNTS + 128)

extern "C" void kernel_launch(void* const* d_in, const int* in_sizes, int n_in,
                              void* d_out, int out_size, void* d_ws, size_t ws_size,
                              hipStream_t stream) {
    const float* x    = (const float*)d_in[0];
    const float* W1   = (const float*)d_in[1];
    const float* b1   = (const float*)d_in[2];
    const float* W2   = (const float*)d_in[3];
    const float* b2   = (const float*)d_in[4];
    const float* Wlin = (const float*)d_in[5];
    const float* blin = (const float*)d_in[6];
    const int* ei     = (const int*)d_in[7];
    const int* batch  = (const int*)d_in[8];
    float* out = (float*)d_out;

    const int* row = ei;            // edge_index[0]
    const int* col = ei + NEDGES;   // edge_index[1]

    float* ws   = (float*)d_ws;
    float* dinv = ws + OFF_DINV;
    float* h1   = ws + OFF_H1;
    float* h2   = ws + OFF_H2;
    float* h3   = ws + OFF_H3;
    float* out1 = ws + OFF_OUT1;
    float* gA   = ws + OFF_GA;
    float* gB   = ws + OFF_GB;
    float* sums = ws + OFF_SUMS;
    float* cnts = ws + OFF_CNTS;

    // ---- norm ----
    hipMemsetAsync(dinv, 0, NNODES * sizeof(float), stream);
    deg_kernel<<<(NEDGES + 255) / 256, 256, 0, stream>>>(col, dinv);
    dinv_kernel<<<(NNODES + 255) / 256, 256, 0, stream>>>(dinv);

    // ---- layer 1 ----
    hipMemsetAsync(h1, 0, 3 * 400000 * sizeof(float), stream);  // h1,h2,h3 contiguous
    prop4<<<(NEDGES + 255) / 256, 256, 0, stream>>>(row, col, dinv, x, h1);
    prop4<<<(NEDGES + 255) / 256, 256, 0, stream>>>(row, col, dinv, h1, h2);
    prop4<<<(NEDGES + 255) / 256, 256, 0, stream>>>(row, col, dinv, h2, h3);
    combine1<<<NNODES / 4, 128, 0, stream>>>(x, h1, h2, h3, W1, b1, out1);

    // ---- layer 2 ----
    hipMemsetAsync(gA, 0, (size_t)NNODES * HID * sizeof(float), stream);
    prop128<<<(NEDGES * 32) / 256, 256, 0, stream>>>(row, col, dinv, out1, gA);
    gemm128<0><<<NNODES / 8, 128, 0, stream>>>(out1, W2 + 0 * 16384, out1);  // in-place overwrite
    gemm128<1><<<NNODES / 8, 128, 0, stream>>>(gA,   W2 + 1 * 16384, out1);
    hipMemsetAsync(gB, 0, (size_t)NNODES * HID * sizeof(float), stream);
    prop128<<<(NEDGES * 32) / 256, 256, 0, stream>>>(row, col, dinv, gA, gB);
    gemm128<1><<<NNODES / 8, 128, 0, stream>>>(gB,   W2 + 2 * 16384, out1);
    hipMemsetAsync(gA, 0, (size_t)NNODES * HID * sizeof(float), stream);
    prop128<<<(NEDGES * 32) / 256, 256, 0, stream>>>(row, col, dinv, gB, gA);
    gemm128<1><<<NNODES / 8, 128, 0, stream>>>(gA,   W2 + 3 * 16384, out1);

    // ---- pool + head ----
    hipMemsetAsync(sums, 0, (16384 + 128) * sizeof(float), stream);
    pool_kernel<<<(NNODES * HID) / 256, 256, 0, stream>>>(out1, b2, batch, sums, cnts);
    head_kernel<<<1, 128, 0, stream>>>(sums, cnts, Wlin, blin, out);
}

// Round 2
// 1014.385 us; speedup vs baseline: 9.9612x; 9.9612x over previous
//
#include <hip/hip_runtime.h>

#define NNODES 100000
#define NEDGES 1600000
#define NGRAPHS 128
#define HID 128

typedef unsigned short ushort_t;

__device__ __forceinline__ float bf2f(unsigned short u) {
    return __uint_as_float(((unsigned)u) << 16);
}
__device__ __forceinline__ unsigned short f2bf(float f) {
    unsigned u = __float_as_uint(f);
    unsigned r = (u + 0x7fffu + ((u >> 16) & 1u)) >> 16;
    return (unsigned short)r;
}

// ---------------- degree (int atomics) ----------------
__global__ void degi_kernel(const int* __restrict__ col, int* __restrict__ degi) {
    int e = blockIdx.x * blockDim.x + threadIdx.x;
    if (e < NEDGES) atomicAdd(&degi[col[e]], 1);
}

__global__ void dinv_kernel(const int* __restrict__ degi, float* __restrict__ dinv) {
    int i = blockIdx.x * blockDim.x + threadIdx.x;
    if (i < NNODES) {
        int d = degi[i];
        dinv[i] = (d > 0) ? rsqrtf((float)d) : 0.0f;
    }
}

// ---------------- single-block exclusive scan: degi -> off ----------------
__global__ void scan_kernel(const int* __restrict__ degi, int* __restrict__ off) {
    __shared__ int wsum[16];
    __shared__ int sh_carry, sh_total;
    int lane = threadIdx.x & 63, wid = threadIdx.x >> 6;
    if (threadIdx.x == 0) sh_carry = 0;
    __syncthreads();
    for (int base = 0; base < NNODES; base += 1024) {
        int i = base + threadIdx.x;
        int v = (i < NNODES) ? degi[i] : 0;
        int incl = v;
#pragma unroll
        for (int d = 1; d < 64; d <<= 1) {
            int t = __shfl_up(incl, d);
            if (lane >= d) incl += t;
        }
        if (lane == 63) wsum[wid] = incl;
        __syncthreads();
        int carry = sh_carry;
        if (wid == 0) {
            int wv = (lane < 16) ? wsum[lane] : 0;
            int wincl = wv;
#pragma unroll
            for (int d = 1; d < 16; d <<= 1) {
                int t = __shfl_up(wincl, d);
                if (lane >= d) wincl += t;
            }
            if (lane < 16) wsum[lane] = wincl - wv;  // exclusive wave offsets
            if (lane == 15) sh_total = wincl;
        }
        __syncthreads();
        if (i < NNODES) off[i] = carry + wsum[wid] + incl - v;  // exclusive scan
        __syncthreads();
        if (threadIdx.x == 0) sh_carry = carry + sh_total;
        __syncthreads();
    }
}

// ---------------- CSR fill (shifts off: after this, node n spans [off[n-1], off[n])) ----------------
__global__ void fill_csr(const int* __restrict__ row, const int* __restrict__ col,
                         const float* __restrict__ dinv,
                         int* __restrict__ off, int* __restrict__ csr_src,
                         float* __restrict__ csr_w) {
    int e = blockIdx.x * blockDim.x + threadIdx.x;
    if (e >= NEDGES) return;
    int r = row[e], c = col[e];
    int p = atomicAdd(&off[c], 1);
    csr_src[p] = r;
    csr_w[p] = dinv[r] * dinv[c];
}

// ---------------- layer-1 gather (F=4, fp32), one thread per node ----------------
__global__ void gprop4(const int* __restrict__ off, const int* __restrict__ csr_src,
                       const float* __restrict__ csr_w,
                       const float* __restrict__ hin, float* __restrict__ hout) {
    int n = blockIdx.x * blockDim.x + threadIdx.x;
    if (n >= NNODES) return;
    int beg = n ? off[n - 1] : 0, end = off[n];
    float4 acc = {0.f, 0.f, 0.f, 0.f};
    for (int k = beg; k < end; k++) {
        int s = csr_src[k];
        float w = csr_w[k];
        float4 v = *(const float4*)(hin + s * 4);
        acc.x += w * v.x; acc.y += w * v.y; acc.z += w * v.z; acc.w += w * v.w;
    }
    *(float4*)(hout + n * 4) = acc;
}

// ---------------- layer-2 gather (F=128, bf16), 32 lanes per node ----------------
__global__ void gprop128(const int* __restrict__ off, const int* __restrict__ csr_src,
                         const float* __restrict__ csr_w,
                         const ushort_t* __restrict__ hin, ushort_t* __restrict__ hout) {
    int t = blockIdx.x * blockDim.x + threadIdx.x;
    int n = t >> 5, lane = t & 31;
    if (n >= NNODES) return;
    int beg = n ? off[n - 1] : 0, end = off[n];
    float4 acc = {0.f, 0.f, 0.f, 0.f};
    for (int k = beg; k < end; k++) {
        int s = csr_src[k];
        float w = csr_w[k];
        uint2 pv = *(const uint2*)(hin + s * HID + lane * 4);
        acc.x += w * __uint_as_float(pv.x << 16);
        acc.y += w * __uint_as_float(pv.x & 0xffff0000u);
        acc.z += w * __uint_as_float(pv.y << 16);
        acc.w += w * __uint_as_float(pv.y & 0xffff0000u);
    }
    uint2 o;
    o.x = (unsigned)f2bf(acc.x) | ((unsigned)f2bf(acc.y) << 16);
    o.y = (unsigned)f2bf(acc.z) | ((unsigned)f2bf(acc.w) << 16);
    *(uint2*)(hout + n * HID + lane * 4) = o;
}

// ---------------- layer-1 combine -> bf16 X ----------------
__global__ void combine1(const float* __restrict__ x, const float* __restrict__ h1,
                         const float* __restrict__ h2, const float* __restrict__ h3,
                         const float* __restrict__ W1, const float* __restrict__ b1,
                         ushort_t* __restrict__ X16) {
    __shared__ float hs[4][16];
    int n0 = blockIdx.x * 4;
    int j = threadIdx.x;  // 0..127
    if (j < 64) {
        int n = j >> 4, v = j & 15, k = v >> 2, i = v & 3;
        const float* src = (k == 0) ? x : (k == 1) ? h1 : (k == 2) ? h2 : h3;
        hs[n][v] = src[(n0 + n) * 4 + i];
    }
    __syncthreads();
    float w[16];
#pragma unroll
    for (int v = 0; v < 16; v++) w[v] = W1[v * 128 + j];
    float bb = b1[j];
#pragma unroll
    for (int n = 0; n < 4; n++) {
        float acc = bb;
#pragma unroll
        for (int v = 0; v < 16; v++) acc += hs[n][v] * w[v];
        X16[(n0 + n) * 128 + j] = f2bf(fmaxf(acc, 0.0f));
    }
}

// ---------------- C (=|+=) A16 @ W, A16 bf16 [N,128], W fp32 [128,128], C fp32 ----------------
template <int ACC>
__global__ void gemm128(const ushort_t* __restrict__ A16, const float* __restrict__ W,
                        float* __restrict__ C) {
    __shared__ float As[8][HID];
    int n0 = blockIdx.x * 8;
    int j = threadIdx.x;
#pragma unroll
    for (int r = 0; r < 8; r++) As[r][j] = bf2f(A16[(n0 + r) * HID + j]);
    __syncthreads();
    float acc[8];
#pragma unroll
    for (int r = 0; r < 8; r++) acc[r] = ACC ? C[(n0 + r) * HID + j] : 0.0f;
    for (int i = 0; i < HID; i += 4) {
        float w0 = W[(i + 0) * HID + j];
        float w1 = W[(i + 1) * HID + j];
        float w2 = W[(i + 2) * HID + j];
        float w3 = W[(i + 3) * HID + j];
#pragma unroll
        for (int r = 0; r < 8; r++) {
            float4 a = *(const float4*)&As[r][i];
            acc[r] += a.x * w0 + a.y * w1 + a.z * w2 + a.w * w3;
        }
    }
#pragma unroll
    for (int r = 0; r < 8; r++) C[(n0 + r) * HID + j] = acc[r];
}

// ---------------- pool: flush-on-graph-change (batch is sorted) ----------------
__global__ void pool2(const float* __restrict__ S, const float* __restrict__ b2,
                      const int* __restrict__ batch,
                      float* __restrict__ sums, float* __restrict__ cnts) {
    int j = threadIdx.x;  // 0..127
    int n0 = blockIdx.x * 128;
    int nend = n0 + 128 < NNODES ? n0 + 128 : NNODES;
    float bb = b2[j];
    float acc = 0.0f;
    int ccnt = 0;
    int gcur = batch[n0];
    for (int n = n0; n < nend; n++) {
        int g = batch[n];
        if (g != gcur) {
            atomicAdd(&sums[gcur * HID + j], acc);
            if (j == 0) atomicAdd(&cnts[gcur], (float)ccnt);
            acc = 0.0f; ccnt = 0; gcur = g;
        }
        acc += fmaxf(S[n * HID + j] + bb, 0.0f);
        ccnt++;
    }
    atomicAdd(&sums[gcur * HID + j], acc);
    if (j == 0) atomicAdd(&cnts[gcur], (float)ccnt);
}

// ---------------- head ----------------
__global__ void head_kernel(const float* __restrict__ sums, const float* __restrict__ cnts,
                            const float* __restrict__ Wlin, const float* __restrict__ blin,
                            float* __restrict__ out) {
    int g = threadIdx.x;
    if (g >= NGRAPHS) return;
    float cnt = fmaxf(cnts[g], 1.0f);
    float l0 = blin[0], l1 = blin[1];
    for (int i = 0; i < HID; i++) {
        float p = sums[g * HID + i] / cnt;
        l0 += p * Wlin[i * 2 + 0];
        l1 += p * Wlin[i * 2 + 1];
    }
    float m = fmaxf(l0, l1);
    float e0 = __expf(l0 - m), e1 = __expf(l1 - m);
    float s = e0 + e1;
    out[g * 2 + 0] = e0 / s;
    out[g * 2 + 1] = e1 / s;
}

// ---------------- workspace layout (in floats / 4-byte units) ----------------
#define OFF_DINV 0
#define OFF_DEGI (OFF_DINV + NNODES)
#define OFF_OFF  (OFF_DEGI + NNODES)
#define OFF_CSRS (OFF_OFF + NNODES)
#define OFF_CSRW (OFF_CSRS + NEDGES)
#define OFF_H1   (OFF_CSRW + NEDGES)
#define OFF_H2   (OFF_H1 + NNODES * 4)
#define OFF_H3   (OFF_H2 + NNODES * 4)
#define OFF_S    (OFF_H3 + NNODES * 4)                  // fp32 [NNODES,128]
#define OFF_P16  (OFF_S + NNODES * HID)                 // bf16 [NNODES,128] = NNODES*64 floats
#define OFF_Q16  (OFF_P16 + NNODES * HID / 2)
#define OFF_SUMS (OFF_Q16 + NNODES * HID / 2)
#define OFF_CNTS (OFF_SUMS + NGRAPHS * HID)

extern "C" void kernel_launch(void* const* d_in, const int* in_sizes, int n_in,
                              void* d_out, int out_size, void* d_ws, size_t ws_size,
                              hipStream_t stream) {
    const float* x    = (const float*)d_in[0];
    const float* W1   = (const float*)d_in[1];
    const float* b1   = (const float*)d_in[2];
    const float* W2   = (const float*)d_in[3];
    const float* b2   = (const float*)d_in[4];
    const float* Wlin = (const float*)d_in[5];
    const float* blin = (const float*)d_in[6];
    const int* ei     = (const int*)d_in[7];
    const int* batch  = (const int*)d_in[8];
    float* out = (float*)d_out;

    const int* row = ei;
    const int* col = ei + NEDGES;

    float* ws = (float*)d_ws;
    float* dinv    = ws + OFF_DINV;
    int*   degi    = (int*)(ws + OFF_DEGI);
    int*   off     = (int*)(ws + OFF_OFF);
    int*   csr_src = (int*)(ws + OFF_CSRS);
    float* csr_w   = ws + OFF_CSRW;
    float* h1      = ws + OFF_H1;
    float* h2      = ws + OFF_H2;
    float* h3      = ws + OFF_H3;
    float* S       = ws + OFF_S;
    ushort_t* P16  = (ushort_t*)(ws + OFF_P16);
    ushort_t* Q16  = (ushort_t*)(ws + OFF_Q16);
    float* sums    = ws + OFF_SUMS;
    float* cnts    = ws + OFF_CNTS;

    // ---- CSR build ----
    hipMemsetAsync(degi, 0, NNODES * sizeof(int), stream);
    hipMemsetAsync(sums, 0, (NGRAPHS * HID + NGRAPHS) * sizeof(float), stream);
    degi_kernel<<<(NEDGES + 255) / 256, 256, 0, stream>>>(col, degi);
    dinv_kernel<<<(NNODES + 255) / 256, 256, 0, stream>>>(degi, dinv);
    scan_kernel<<<1, 1024, 0, stream>>>(degi, off);
    fill_csr<<<(NEDGES + 255) / 256, 256, 0, stream>>>(row, col, dinv, off, csr_src, csr_w);

    // ---- layer 1 (fp32, F=4) ----
    gprop4<<<(NNODES + 255) / 256, 256, 0, stream>>>(off, csr_src, csr_w, x, h1);
    gprop4<<<(NNODES + 255) / 256, 256, 0, stream>>>(off, csr_src, csr_w, h1, h2);
    gprop4<<<(NNODES + 255) / 256, 256, 0, stream>>>(off, csr_src, csr_w, h2, h3);
    combine1<<<NNODES / 4, 128, 0, stream>>>(x, h1, h2, h3, W1, b1, P16);

    // ---- layer 2 (bf16 hops, fp32 accum S) ----
    gemm128<0><<<NNODES / 8, 128, 0, stream>>>(P16, W2 + 0 * 16384, S);
    gprop128<<<(NNODES * 32) / 256, 256, 0, stream>>>(off, csr_src, csr_w, P16, Q16);
    gemm128<1><<<NNODES / 8, 128, 0, stream>>>(Q16, W2 + 1 * 16384, S);
    gprop128<<<(NNODES * 32) / 256, 256, 0, stream>>>(off, csr_src, csr_w, Q16, P16);
    gemm128<1><<<NNODES / 8, 128, 0, stream>>>(P16, W2 + 2 * 16384, S);
    gprop128<<<(NNODES * 32) / 256, 256, 0, stream>>>(off, csr_src, csr_w, P16, Q16);
    gemm128<1><<<NNODES / 8, 128, 0, stream>>>(Q16, W2 + 3 * 16384, S);

    // ---- pool + head ----
    pool2<<<(NNODES + 127) / 128, 128, 0, stream>>>(S, b2, batch, sums, cnts);
    head_kernel<<<1, 128, 0, stream>>>(sums, cnts, Wlin, blin, out);
}

// Round 3
// 551.671 us; speedup vs baseline: 18.3162x; 1.8387x over previous
//
#include <hip/hip_runtime.h>

#define NNODES 100000
#define NEDGES 1600000
#define NGRAPHS 128
#define HID 128
#define NB1 ((NNODES + 1023) / 1024)   // 98 scan blocks

typedef unsigned short ushort_t;
typedef __attribute__((ext_vector_type(8))) short short8;
typedef __attribute__((ext_vector_type(4))) float floatx4;

__device__ __forceinline__ float bf2f(ushort_t u) {
    return __uint_as_float(((unsigned)u) << 16);
}
__device__ __forceinline__ ushort_t f2bf(float f) {
    unsigned u = __float_as_uint(f);
    return (ushort_t)((u + 0x7fffu + ((u >> 16) & 1u)) >> 16);
}

// ---------------- degree / dinv ----------------
__global__ void degi_kernel(const int* __restrict__ col, int* __restrict__ degi) {
    int e = blockIdx.x * blockDim.x + threadIdx.x;
    if (e < NEDGES) atomicAdd(&degi[col[e]], 1);
}

__global__ void dinv_kernel(const int* __restrict__ degi, float* __restrict__ dinv) {
    int i = blockIdx.x * blockDim.x + threadIdx.x;
    if (i < NNODES) {
        int d = degi[i];
        dinv[i] = (d > 0) ? rsqrtf((float)d) : 0.0f;
    }
}

// ---------------- 3-kernel exclusive scan ----------------
__global__ void scan1(const int* __restrict__ degi, int* __restrict__ off,
                      int* __restrict__ partials) {
    __shared__ int wsum[16];
    int i = blockIdx.x * 1024 + threadIdx.x;
    int lane = threadIdx.x & 63, wid = threadIdx.x >> 6;
    int v = (i < NNODES) ? degi[i] : 0;
    int incl = v;
#pragma unroll
    for (int d = 1; d < 64; d <<= 1) { int t = __shfl_up(incl, d); if (lane >= d) incl += t; }
    if (lane == 63) wsum[wid] = incl;
    __syncthreads();
    if (wid == 0) {
        int wv = (lane < 16) ? wsum[lane] : 0;
        int wincl = wv;
#pragma unroll
        for (int d = 1; d < 16; d <<= 1) { int t = __shfl_up(wincl, d); if (lane >= d) wincl += t; }
        if (lane < 16) wsum[lane] = wincl - wv;   // exclusive wave offsets
        if (lane == 15) partials[blockIdx.x] = wincl;
    }
    __syncthreads();
    if (i < NNODES) off[i] = wsum[wid] + incl - v;   // block-local exclusive
}

__global__ void scan2(int* __restrict__ partials) {
    int lane = threadIdx.x;  // 64 threads, 1 block
    int c = 0;
    for (int base = 0; base < NB1; base += 64) {
        int i = base + lane;
        int v = (i < NB1) ? partials[i] : 0;
        int incl = v;
#pragma unroll
        for (int d = 1; d < 64; d <<= 1) { int t = __shfl_up(incl, d); if (lane >= d) incl += t; }
        if (i < NB1) partials[i] = c + incl - v;
        c += __shfl(incl, 63);
    }
}

__global__ void scan3(int* __restrict__ off, const int* __restrict__ partials) {
    int i = blockIdx.x * 256 + threadIdx.x;
    if (i < NNODES) off[i] += partials[i >> 10];
}

// ---------------- CSR fill, packed (src, weight) in one 8B store ----------------
__global__ void fill_csr(const int* __restrict__ row, const int* __restrict__ col,
                         const float* __restrict__ dinv,
                         int* __restrict__ off, uint2* __restrict__ csr) {
    int e = blockIdx.x * blockDim.x + threadIdx.x;
    if (e >= NEDGES) return;
    int r = row[e], c = col[e];
    int p = atomicAdd(&off[c], 1);
    csr[p] = make_uint2((unsigned)r, __float_as_uint(dinv[r] * dinv[c]));
}

// ---------------- layer-1 gather (F=4, fp32), unroll 2 ----------------
__global__ void gprop4(const int* __restrict__ off, const uint2* __restrict__ csr,
                       const float* __restrict__ hin, float* __restrict__ hout) {
    int n = blockIdx.x * 256 + threadIdx.x;
    if (n >= NNODES) return;
    int k = n ? off[n - 1] : 0;
    int end = off[n];
    float4 acc = {0.f, 0.f, 0.f, 0.f};
    for (; k + 1 < end; k += 2) {
        uint2 e0 = csr[k], e1 = csr[k + 1];
        float4 v0 = *(const float4*)(hin + e0.x * 4);
        float4 v1 = *(const float4*)(hin + e1.x * 4);
        float w0 = __uint_as_float(e0.y), w1 = __uint_as_float(e1.y);
        acc.x += w0 * v0.x + w1 * v1.x;
        acc.y += w0 * v0.y + w1 * v1.y;
        acc.z += w0 * v0.z + w1 * v1.z;
        acc.w += w0 * v0.w + w1 * v1.w;
    }
    if (k < end) {
        uint2 e = csr[k];
        float4 v = *(const float4*)(hin + e.x * 4);
        float w = __uint_as_float(e.y);
        acc.x += w * v.x; acc.y += w * v.y; acc.z += w * v.z; acc.w += w * v.w;
    }
    *(float4*)(hout + n * 4) = acc;
}

// ---------------- layer-2 gather (F=128 bf16), 16 lanes/node, uint4 loads, unroll 2 ----------------
__global__ void gprop128(const int* __restrict__ off, const uint2* __restrict__ csr,
                         const ushort_t* __restrict__ hin, ushort_t* __restrict__ hout) {
    int t = blockIdx.x * 256 + threadIdx.x;
    int n = t >> 4, lane = t & 15;
    int k = n ? off[n - 1] : 0;
    int end = off[n];
    int fo = lane * 8;
    float a0 = 0.f, a1 = 0.f, a2 = 0.f, a3 = 0.f, a4 = 0.f, a5 = 0.f, a6 = 0.f, a7 = 0.f;
    for (; k + 1 < end; k += 2) {
        uint2 e0 = csr[k], e1 = csr[k + 1];
        uint4 v0 = *(const uint4*)(hin + e0.x * HID + fo);
        uint4 v1 = *(const uint4*)(hin + e1.x * HID + fo);
        float w0 = __uint_as_float(e0.y), w1 = __uint_as_float(e1.y);
        a0 += w0 * __uint_as_float(v0.x << 16);
        a1 += w0 * __uint_as_float(v0.x & 0xffff0000u);
        a2 += w0 * __uint_as_float(v0.y << 16);
        a3 += w0 * __uint_as_float(v0.y & 0xffff0000u);
        a4 += w0 * __uint_as_float(v0.z << 16);
        a5 += w0 * __uint_as_float(v0.z & 0xffff0000u);
        a6 += w0 * __uint_as_float(v0.w << 16);
        a7 += w0 * __uint_as_float(v0.w & 0xffff0000u);
        a0 += w1 * __uint_as_float(v1.x << 16);
        a1 += w1 * __uint_as_float(v1.x & 0xffff0000u);
        a2 += w1 * __uint_as_float(v1.y << 16);
        a3 += w1 * __uint_as_float(v1.y & 0xffff0000u);
        a4 += w1 * __uint_as_float(v1.z << 16);
        a5 += w1 * __uint_as_float(v1.z & 0xffff0000u);
        a6 += w1 * __uint_as_float(v1.w << 16);
        a7 += w1 * __uint_as_float(v1.w & 0xffff0000u);
    }
    if (k < end) {
        uint2 e = csr[k];
        uint4 v = *(const uint4*)(hin + e.x * HID + fo);
        float w = __uint_as_float(e.y);
        a0 += w * __uint_as_float(v.x << 16);
        a1 += w * __uint_as_float(v.x & 0xffff0000u);
        a2 += w * __uint_as_float(v.y << 16);
        a3 += w * __uint_as_float(v.y & 0xffff0000u);
        a4 += w * __uint_as_float(v.z << 16);
        a5 += w * __uint_as_float(v.z & 0xffff0000u);
        a6 += w * __uint_as_float(v.w << 16);
        a7 += w * __uint_as_float(v.w & 0xffff0000u);
    }
    uint4 o;
    o.x = (unsigned)f2bf(a0) | ((unsigned)f2bf(a1) << 16);
    o.y = (unsigned)f2bf(a2) | ((unsigned)f2bf(a3) << 16);
    o.z = (unsigned)f2bf(a4) | ((unsigned)f2bf(a5) << 16);
    o.w = (unsigned)f2bf(a6) | ((unsigned)f2bf(a7) << 16);
    *(uint4*)(hout + n * HID + fo) = o;
}

// ---------------- layer-1 combine -> bf16 P0 ----------------
__global__ void combine1(const float* __restrict__ x, const float* __restrict__ h1,
                         const float* __restrict__ h2, const float* __restrict__ h3,
                         const float* __restrict__ W1, const float* __restrict__ b1,
                         ushort_t* __restrict__ P0) {
    __shared__ float hs[4][16];
    int n0 = blockIdx.x * 4;
    int j = threadIdx.x;  // 0..127
    if (j < 64) {
        int n = j >> 4, v = j & 15, k = v >> 2, i = v & 3;
        const float* src = (k == 0) ? x : (k == 1) ? h1 : (k == 2) ? h2 : h3;
        hs[n][v] = src[(n0 + n) * 4 + i];
    }
    __syncthreads();
    float w[16];
#pragma unroll
    for (int v = 0; v < 16; v++) w[v] = W1[v * 128 + j];
    float bb = b1[j];
#pragma unroll
    for (int n = 0; n < 4; n++) {
        float acc = bb;
#pragma unroll
        for (int v = 0; v < 16; v++) acc += hs[n][v] * w[v];
        P0[(n0 + n) * 128 + j] = f2bf(fmaxf(acc, 0.0f));
    }
}

// ---------------- W2 transpose to B-fragment-friendly bf16: Wt[j][k] (k=hop*128+i) ----------------
__global__ void wt_kernel(const float* __restrict__ W2, ushort_t* __restrict__ Wt) {
    int t = blockIdx.x * 256 + threadIdx.x;
    if (t >= 512 * 128) return;
    int j = t >> 9, k = t & 511;
    Wt[t] = f2bf(W2[k * 128 + j]);   // W2 flat: (hop*128+i)*128 + j = k*128 + j
}

// ---------------- fused MFMA: S = sum_hop P_hop @ W2[hop] (K=512), bf16 out ----------------
__global__ __launch_bounds__(256) void gemm4(
    const ushort_t* __restrict__ P0, const ushort_t* __restrict__ P1,
    const ushort_t* __restrict__ P2, const ushort_t* __restrict__ P3,
    const ushort_t* __restrict__ Wt, ushort_t* __restrict__ S16) {
    int tid = threadIdx.x;
    int w = tid >> 6, lane = tid & 63;
    int r16 = lane & 15, kg = lane >> 4;
    int mblk = blockIdx.x * 128 + w * 32;   // this wave's 32-node tile
    int node0 = mblk + r16;                 // A rows, subtile 0
    int node1 = node0 + 16;                 // subtile 1
    floatx4 acc[2][8];
#pragma unroll
    for (int s = 0; s < 2; s++)
#pragma unroll
        for (int n = 0; n < 8; n++) acc[s][n] = (floatx4){0.f, 0.f, 0.f, 0.f};
    const ushort_t* Ps[4] = {P0, P1, P2, P3};
#pragma unroll
    for (int hop = 0; hop < 4; hop++) {
        const ushort_t* P = Ps[hop];
#pragma unroll
        for (int k0 = 0; k0 < 128; k0 += 32) {
            int f = k0 + kg * 8;
            short8 a0 = {0, 0, 0, 0, 0, 0, 0, 0}, a1 = {0, 0, 0, 0, 0, 0, 0, 0};
            if (node0 < NNODES) a0 = *(const short8*)(P + node0 * HID + f);
            if (node1 < NNODES) a1 = *(const short8*)(P + node1 * HID + f);
            int kk = hop * 128 + f;
#pragma unroll
            for (int n = 0; n < 8; n++) {
                short8 b = *(const short8*)(Wt + (n * 16 + r16) * 512 + kk);
                acc[0][n] = __builtin_amdgcn_mfma_f32_16x16x32_bf16(a0, b, acc[0][n], 0, 0, 0);
                acc[1][n] = __builtin_amdgcn_mfma_f32_16x16x32_bf16(a1, b, acc[1][n], 0, 0, 0);
            }
        }
    }
    // C/D layout: col = lane&15, row = (lane>>4)*4 + reg
#pragma unroll
    for (int s = 0; s < 2; s++)
#pragma unroll
        for (int r = 0; r < 4; r++) {
            int node = mblk + s * 16 + kg * 4 + r;
            if (node < NNODES) {
#pragma unroll
                for (int n = 0; n < 8; n++)
                    S16[node * HID + n * 16 + r16] = f2bf(acc[s][n][r]);
            }
        }
}

// ---------------- graph boundaries (batch sorted): first/last node per graph ----------------
__global__ void bounds_kernel(const int* __restrict__ batch,
                              int* __restrict__ first, int* __restrict__ last) {
    int n = blockIdx.x * 256 + threadIdx.x;
    if (n >= NNODES) return;
    int g = batch[n];
    if (n == 0 || batch[n - 1] != g) first[g] = n;
    if (n == NNODES - 1 || batch[n + 1] != g) last[g] = n;
}

// ---------------- pool: relu(S + b2), segmented sums (batch sorted) ----------------
__global__ void pool2(const ushort_t* __restrict__ S16, const float* __restrict__ b2,
                      const int* __restrict__ batch, float* __restrict__ sums) {
    int j = threadIdx.x;  // 0..127
    int n0 = blockIdx.x * 128;
    int nend = n0 + 128 < NNODES ? n0 + 128 : NNODES;
    float bb = b2[j];
    float acc = 0.0f;
    int gcur = batch[n0];
    for (int n = n0; n < nend; n++) {
        int g = batch[n];
        if (g != gcur) {
            atomicAdd(&sums[gcur * HID + j], acc);
            acc = 0.0f; gcur = g;
        }
        acc += fmaxf(bf2f(S16[n * HID + j]) + bb, 0.0f);
    }
    atomicAdd(&sums[gcur * HID + j], acc);
}

// ---------------- head ----------------
__global__ void head_kernel(const float* __restrict__ sums, const int* __restrict__ first,
                            const int* __restrict__ last,
                            const float* __restrict__ Wlin, const float* __restrict__ blin,
                            float* __restrict__ out) {
    int g = threadIdx.x;
    if (g >= NGRAPHS) return;
    int f = first[g];
    float cnt = (f >= 0) ? (float)(last[g] - f + 1) : 1.0f;
    float l0 = blin[0], l1 = blin[1];
    for (int i = 0; i < HID; i++) {
        float p = sums[g * HID + i] / cnt;
        l0 += p * Wlin[i * 2 + 0];
        l1 += p * Wlin[i * 2 + 1];
    }
    float m = fmaxf(l0, l1);
    float e0 = __expf(l0 - m), e1 = __expf(l1 - m);
    float s = e0 + e1;
    out[g * 2 + 0] = e0 / s;
    out[g * 2 + 1] = e1 / s;
}

// ---------------- workspace layout (4-byte units) ----------------
#define OFF_DINV  0
#define OFF_DEGI  (OFF_DINV + NNODES)
#define OFF_OFF   (OFF_DEGI + NNODES)
#define OFF_PART  (OFF_OFF + NNODES)
#define OFF_CSR   (OFF_PART + 128)                 // uint2[NEDGES] = 2*NEDGES words (8B-aligned: even)
#define OFF_P0    (OFF_CSR + 2 * NEDGES)
#define OFF_P1    (OFF_P0 + NNODES * HID / 2)      // bf16 buffers: NNODES*128*2B = NNODES*64 words
#define OFF_P2    (OFF_P1 + NNODES * HID / 2)
#define OFF_P3    (OFF_P2 + NNODES * HID / 2)
#define OFF_S16   (OFF_P3 + NNODES * HID / 2)      // bf16 S; h1..h3 alias its head (dead before gemm4)
#define OFF_H1    OFF_S16
#define OFF_H2    (OFF_H1 + NNODES * 4)
#define OFF_H3    (OFF_H2 + NNODES * 4)
#define OFF_WT    (OFF_S16 + NNODES * HID / 2)     // 512*128 bf16 = 32768 words
#define OFF_SUMS  (OFF_WT + 32768)
#define OFF_FIRST (OFF_SUMS + NGRAPHS * HID)
#define OFF_LAST  (OFF_FIRST + NGRAPHS)

extern "C" void kernel_launch(void* const* d_in, const int* in_sizes, int n_in,
                              void* d_out, int out_size, void* d_ws, size_t ws_size,
                              hipStream_t stream) {
    const float* x    = (const float*)d_in[0];
    const float* W1   = (const float*)d_in[1];
    const float* b1   = (const float*)d_in[2];
    const float* W2   = (const float*)d_in[3];
    const float* b2   = (const float*)d_in[4];
    const float* Wlin = (const float*)d_in[5];
    const float* blin = (const float*)d_in[6];
    const int* ei     = (const int*)d_in[7];
    const int* batch  = (const int*)d_in[8];
    float* out = (float*)d_out;

    const int* row = ei;
    const int* col = ei + NEDGES;

    float* ws = (float*)d_ws;
    float* dinv    = ws + OFF_DINV;
    int*   degi    = (int*)(ws + OFF_DEGI);
    int*   off     = (int*)(ws + OFF_OFF);
    int*   part    = (int*)(ws + OFF_PART);
    uint2* csr     = (uint2*)(ws + OFF_CSR);
    ushort_t* P0   = (ushort_t*)(ws + OFF_P0);
    ushort_t* P1   = (ushort_t*)(ws + OFF_P1);
    ushort_t* P2   = (ushort_t*)(ws + OFF_P2);
    ushort_t* P3   = (ushort_t*)(ws + OFF_P3);
    ushort_t* S16  = (ushort_t*)(ws + OFF_S16);
    float* h1      = ws + OFF_H1;
    float* h2      = ws + OFF_H2;
    float* h3      = ws + OFF_H3;
    ushort_t* Wt   = (ushort_t*)(ws + OFF_WT);
    float* sums    = ws + OFF_SUMS;
    int*   first   = (int*)(ws + OFF_FIRST);
    int*   last    = (int*)(ws + OFF_LAST);

    // ---- init ----
    hipMemsetAsync(degi, 0, NNODES * sizeof(int), stream);
    hipMemsetAsync(sums, 0, NGRAPHS * HID * sizeof(float), stream);
    hipMemsetAsync(first, 0xFF, 2 * NGRAPHS * sizeof(int), stream);

    // ---- CSR build ----
    degi_kernel<<<NEDGES / 256, 256, 0, stream>>>(col, degi);
    dinv_kernel<<<(NNODES + 255) / 256, 256, 0, stream>>>(degi, dinv);
    scan1<<<NB1, 1024, 0, stream>>>(degi, off, part);
    scan2<<<1, 64, 0, stream>>>(part);
    scan3<<<(NNODES + 255) / 256, 256, 0, stream>>>(off, part);
    fill_csr<<<NEDGES / 256, 256, 0, stream>>>(row, col, dinv, off, csr);
    wt_kernel<<<(512 * 128) / 256, 256, 0, stream>>>(W2, Wt);
    bounds_kernel<<<(NNODES + 255) / 256, 256, 0, stream>>>(batch, first, last);

    // ---- layer 1 (fp32, F=4) ----
    gprop4<<<(NNODES + 255) / 256, 256, 0, stream>>>(off, csr, x, h1);
    gprop4<<<(NNODES + 255) / 256, 256, 0, stream>>>(off, csr, h1, h2);
    gprop4<<<(NNODES + 255) / 256, 256, 0, stream>>>(off, csr, h2, h3);
    combine1<<<NNODES / 4, 128, 0, stream>>>(x, h1, h2, h3, W1, b1, P0);

    // ---- layer 2 hops (bf16) ----
    gprop128<<<(NNODES * 16) / 256, 256, 0, stream>>>(off, csr, P0, P1);
    gprop128<<<(NNODES * 16) / 256, 256, 0, stream>>>(off, csr, P1, P2);
    gprop128<<<(NNODES * 16) / 256, 256, 0, stream>>>(off, csr, P2, P3);

    // ---- fused MFMA combine (K=512) ----
    gemm4<<<(NNODES + 127) / 128, 256, 0, stream>>>(P0, P1, P2, P3, Wt, S16);

    // ---- pool + head ----
    pool2<<<(NNODES + 127) / 128, 128, 0, stream>>>(S16, b2, batch, sums);
    head_kernel<<<1, 128, 0, stream>>>(sums, first, last, Wlin, blin, out);
}

// Round 4
// 472.926 us; speedup vs baseline: 21.3659x; 1.1665x over previous
//
#include <hip/hip_runtime.h>

#define NNODES 100000
#define NEDGES 1600000
#define NGRAPHS 128
#define HID 128
#define NBKT 782            // ceil(100000/128)
#define CHUNK 8192
#define NCHB ((NEDGES + CHUNK - 1) / CHUNK)   // 196
#define MAXB 3072           // bucket edge cap (mean 2048, sigma ~45)

typedef unsigned short ushort_t;
typedef unsigned int uint_t;
typedef __attribute__((ext_vector_type(8))) short short8;
typedef __attribute__((ext_vector_type(4))) float floatx4;

__device__ __forceinline__ float bf2f(ushort_t u) {
    return __uint_as_float(((unsigned)u) << 16);
}
__device__ __forceinline__ ushort_t f2bf(float f) {
    unsigned u = __float_as_uint(f);
    return (ushort_t)((u + 0x7fffu + ((u >> 16) & 1u)) >> 16);
}

// ---------------- bucket histogram (LDS-staged) ----------------
__global__ void hist_k(const int* __restrict__ col, int* __restrict__ bcnt) {
    __shared__ int l[NBKT];
    for (int i = threadIdx.x; i < NBKT; i += 256) l[i] = 0;
    __syncthreads();
    int base = blockIdx.x * CHUNK;
    int lim = base + CHUNK < NEDGES ? base + CHUNK : NEDGES;
    for (int e = base + threadIdx.x; e < lim; e += 256)
        atomicAdd(&l[col[e] >> 7], 1);
    __syncthreads();
    for (int i = threadIdx.x; i < NBKT; i += 256)
        if (l[i]) atomicAdd(&bcnt[i], l[i]);
}

// ---------------- scan 782 buckets (single block) ----------------
__global__ void bscan_k(const int* __restrict__ bcnt, int* __restrict__ bbase,
                        int* __restrict__ gc) {
    __shared__ int l[1024];
    int t = threadIdx.x;
    int v0 = (t < NBKT) ? bcnt[t] : 0;
    l[t] = v0;
    __syncthreads();
    for (int d = 1; d < 1024; d <<= 1) {
        int v = (t >= d) ? l[t - d] : 0;
        __syncthreads();
        l[t] += v;
        __syncthreads();
    }
    if (t < NBKT) { int ex = l[t] - v0; bbase[t] = ex; gc[t] = ex; }
    if (t == 0) bbase[NBKT] = NEDGES;
}

// ---------------- bucket scatter: one range-claim atomic per (block,bucket) ----------------
__global__ void bfill_k(const int* __restrict__ row, const int* __restrict__ col,
                        int* __restrict__ gc, uint_t* __restrict__ entry) {
    __shared__ int lcnt[NBKT], lbase[NBKT];
    for (int i = threadIdx.x; i < NBKT; i += 256) lcnt[i] = 0;
    __syncthreads();
    int base = blockIdx.x * CHUNK;
    int lim = base + CHUNK < NEDGES ? base + CHUNK : NEDGES;
    for (int e = base + threadIdx.x; e < lim; e += 256)
        atomicAdd(&lcnt[col[e] >> 7], 1);
    __syncthreads();
    for (int i = threadIdx.x; i < NBKT; i += 256) {
        int c = lcnt[i];
        lbase[i] = c ? atomicAdd(&gc[i], c) : 0;
        lcnt[i] = 0;   // reuse as fill cursor
    }
    __syncthreads();
    for (int e = base + threadIdx.x; e < lim; e += 256) {
        int c = col[e];
        int b = c >> 7;
        int pos = lbase[b] + atomicAdd(&lcnt[b], 1);
        entry[pos] = (uint_t)row[e] | ((uint_t)(c & 127) << 17);
    }
}

// ---------------- per-bucket LDS counting sort -> csr_src, degi, off ----------------
__global__ void sortb_k(const uint_t* __restrict__ entry, const int* __restrict__ bbase,
                        int* __restrict__ csr_src, int* __restrict__ degi,
                        int* __restrict__ off) {
    __shared__ uint_t ents[MAXB];
    __shared__ uint_t sorted[MAXB];
    __shared__ int ncnt[128], nsc[128], nfill[128];
    int b = blockIdx.x;
    int base = bbase[b];
    int cnt = bbase[b + 1] - base;
    if (cnt > MAXB) cnt = MAXB;   // never triggers for this input (22-sigma margin)
    int t = threadIdx.x;
    if (t < 128) { ncnt[t] = 0; nfill[t] = 0; }
    __syncthreads();
    for (int i = t; i < cnt; i += 256) {
        uint_t v = entry[base + i];
        ents[i] = v;
        atomicAdd(&ncnt[v >> 17], 1);
    }
    __syncthreads();
    if (t < 128) nsc[t] = ncnt[t];
    __syncthreads();
    for (int d = 1; d < 128; d <<= 1) {
        int v = (t >= d && t < 128) ? nsc[t - d] : 0;
        __syncthreads();
        if (t < 128) nsc[t] += v;   // inclusive scan
        __syncthreads();
    }
    if (t < 128) {
        int n = b * 128 + t;
        if (n < NNODES) { degi[n] = ncnt[t]; off[n] = base + nsc[t]; }
        nsc[t] -= ncnt[t];          // exclusive
    }
    __syncthreads();
    for (int i = t; i < cnt; i += 256) {
        uint_t v = ents[i];
        int dl = v >> 17;
        int pos = nsc[dl] + atomicAdd(&nfill[dl], 1);
        sorted[pos] = v & 0x1FFFFu;
    }
    __syncthreads();
    for (int i = t; i < cnt; i += 256) csr_src[base + i] = (int)sorted[i];
}

__global__ void dinv_kernel(const int* __restrict__ degi, float* __restrict__ dinv) {
    int i = blockIdx.x * blockDim.x + threadIdx.x;
    if (i < NNODES) {
        int d = degi[i];
        dinv[i] = (d > 0) ? rsqrtf((float)d) : 0.0f;
    }
}

// ---------------- layer-1 gather (F=4, fp32), runtime weights, unroll 2 ----------------
__global__ void gprop4(const int* __restrict__ off, const int* __restrict__ csr_src,
                       const float* __restrict__ dinv,
                       const float* __restrict__ hin, float* __restrict__ hout) {
    int n = blockIdx.x * 256 + threadIdx.x;
    if (n >= NNODES) return;
    int k = n ? off[n - 1] : 0;
    int end = off[n];
    float dn = dinv[n];
    float4 acc = {0.f, 0.f, 0.f, 0.f};
    for (; k + 1 < end; k += 2) {
        int s0 = csr_src[k], s1 = csr_src[k + 1];
        float w0 = dinv[s0] * dn, w1 = dinv[s1] * dn;
        float4 v0 = *(const float4*)(hin + s0 * 4);
        float4 v1 = *(const float4*)(hin + s1 * 4);
        acc.x += w0 * v0.x + w1 * v1.x;
        acc.y += w0 * v0.y + w1 * v1.y;
        acc.z += w0 * v0.z + w1 * v1.z;
        acc.w += w0 * v0.w + w1 * v1.w;
    }
    if (k < end) {
        int s = csr_src[k];
        float w = dinv[s] * dn;
        float4 v = *(const float4*)(hin + s * 4);
        acc.x += w * v.x; acc.y += w * v.y; acc.z += w * v.z; acc.w += w * v.w;
    }
    *(float4*)(hout + n * 4) = acc;
}

// ---------------- layer-2 gather (F=128 bf16), 16 lanes/node, runtime weights ----------------
__global__ void gprop128(const int* __restrict__ off, const int* __restrict__ csr_src,
                         const float* __restrict__ dinv,
                         const ushort_t* __restrict__ hin, ushort_t* __restrict__ hout) {
    int t = blockIdx.x * 256 + threadIdx.x;
    int n = t >> 4, lane = t & 15;
    if (n >= NNODES) return;
    int k = n ? off[n - 1] : 0;
    int end = off[n];
    float dn = dinv[n];
    int fo = lane * 8;
    float a0 = 0.f, a1 = 0.f, a2 = 0.f, a3 = 0.f, a4 = 0.f, a5 = 0.f, a6 = 0.f, a7 = 0.f;
    for (; k + 1 < end; k += 2) {
        int s0 = csr_src[k], s1 = csr_src[k + 1];
        float w0 = dinv[s0] * dn, w1 = dinv[s1] * dn;
        uint4 v0 = *(const uint4*)(hin + s0 * HID + fo);
        uint4 v1 = *(const uint4*)(hin + s1 * HID + fo);
        a0 += w0 * __uint_as_float(v0.x << 16);
        a1 += w0 * __uint_as_float(v0.x & 0xffff0000u);
        a2 += w0 * __uint_as_float(v0.y << 16);
        a3 += w0 * __uint_as_float(v0.y & 0xffff0000u);
        a4 += w0 * __uint_as_float(v0.z << 16);
        a5 += w0 * __uint_as_float(v0.z & 0xffff0000u);
        a6 += w0 * __uint_as_float(v0.w << 16);
        a7 += w0 * __uint_as_float(v0.w & 0xffff0000u);
        a0 += w1 * __uint_as_float(v1.x << 16);
        a1 += w1 * __uint_as_float(v1.x & 0xffff0000u);
        a2 += w1 * __uint_as_float(v1.y << 16);
        a3 += w1 * __uint_as_float(v1.y & 0xffff0000u);
        a4 += w1 * __uint_as_float(v1.z << 16);
        a5 += w1 * __uint_as_float(v1.z & 0xffff0000u);
        a6 += w1 * __uint_as_float(v1.w << 16);
        a7 += w1 * __uint_as_float(v1.w & 0xffff0000u);
    }
    if (k < end) {
        int s = csr_src[k];
        float w = dinv[s] * dn;
        uint4 v = *(const uint4*)(hin + s * HID + fo);
        a0 += w * __uint_as_float(v.x << 16);
        a1 += w * __uint_as_float(v.x & 0xffff0000u);
        a2 += w * __uint_as_float(v.y << 16);
        a3 += w * __uint_as_float(v.y & 0xffff0000u);
        a4 += w * __uint_as_float(v.z << 16);
        a5 += w * __uint_as_float(v.z & 0xffff0000u);
        a6 += w * __uint_as_float(v.w << 16);
        a7 += w * __uint_as_float(v.w & 0xffff0000u);
    }
    uint4 o;
    o.x = (unsigned)f2bf(a0) | ((unsigned)f2bf(a1) << 16);
    o.y = (unsigned)f2bf(a2) | ((unsigned)f2bf(a3) << 16);
    o.z = (unsigned)f2bf(a4) | ((unsigned)f2bf(a5) << 16);
    o.w = (unsigned)f2bf(a6) | ((unsigned)f2bf(a7) << 16);
    *(uint4*)(hout + n * HID + fo) = o;
}

// ---------------- layer-1 combine -> bf16 P0 ----------------
__global__ void combine1(const float* __restrict__ x, const float* __restrict__ h1,
                         const float* __restrict__ h2, const float* __restrict__ h3,
                         const float* __restrict__ W1, const float* __restrict__ b1,
                         ushort_t* __restrict__ P0) {
    __shared__ float hs[4][16];
    int n0 = blockIdx.x * 4;
    int j = threadIdx.x;  // 0..127
    if (j < 64) {
        int n = j >> 4, v = j & 15, k = v >> 2, i = v & 3;
        const float* src = (k == 0) ? x : (k == 1) ? h1 : (k == 2) ? h2 : h3;
        hs[n][v] = src[(n0 + n) * 4 + i];
    }
    __syncthreads();
    float w[16];
#pragma unroll
    for (int v = 0; v < 16; v++) w[v] = W1[v * 128 + j];
    float bb = b1[j];
#pragma unroll
    for (int n = 0; n < 4; n++) {
        float acc = bb;
#pragma unroll
        for (int v = 0; v < 16; v++) acc += hs[n][v] * w[v];
        P0[(n0 + n) * 128 + j] = f2bf(fmaxf(acc, 0.0f));
    }
}

// ---------------- W2 transpose to bf16: Wt[j][k] (k = hop*128+i) ----------------
__global__ void wt_kernel(const float* __restrict__ W2, ushort_t* __restrict__ Wt) {
    int t = blockIdx.x * 256 + threadIdx.x;
    if (t >= 512 * 128) return;
    int j = t >> 9, k = t & 511;
    Wt[t] = f2bf(W2[k * 128 + j]);
}

// ---------------- fused MFMA: S = sum_hop P_hop @ W2[hop] (K=512), bf16 out ----------------
__global__ __launch_bounds__(256) void gemm4(
    const ushort_t* __restrict__ P0, const ushort_t* __restrict__ P1,
    const ushort_t* __restrict__ P2, const ushort_t* __restrict__ P3,
    const ushort_t* __restrict__ Wt, ushort_t* __restrict__ S16) {
    int tid = threadIdx.x;
    int w = tid >> 6, lane = tid & 63;
    int r16 = lane & 15, kg = lane >> 4;
    int mblk = blockIdx.x * 128 + w * 32;
    int node0 = mblk + r16;
    int node1 = node0 + 16;
    floatx4 acc[2][8];
#pragma unroll
    for (int s = 0; s < 2; s++)
#pragma unroll
        for (int n = 0; n < 8; n++) acc[s][n] = (floatx4){0.f, 0.f, 0.f, 0.f};
    const ushort_t* Ps[4] = {P0, P1, P2, P3};
#pragma unroll
    for (int hop = 0; hop < 4; hop++) {
        const ushort_t* P = Ps[hop];
#pragma unroll
        for (int k0 = 0; k0 < 128; k0 += 32) {
            int f = k0 + kg * 8;
            short8 a0 = {0, 0, 0, 0, 0, 0, 0, 0}, a1 = {0, 0, 0, 0, 0, 0, 0, 0};
            if (node0 < NNODES) a0 = *(const short8*)(P + node0 * HID + f);
            if (node1 < NNODES) a1 = *(const short8*)(P + node1 * HID + f);
            int kk = hop * 128 + f;
#pragma unroll
            for (int n = 0; n < 8; n++) {
                short8 b = *(const short8*)(Wt + (n * 16 + r16) * 512 + kk);
                acc[0][n] = __builtin_amdgcn_mfma_f32_16x16x32_bf16(a0, b, acc[0][n], 0, 0, 0);
                acc[1][n] = __builtin_amdgcn_mfma_f32_16x16x32_bf16(a1, b, acc[1][n], 0, 0, 0);
            }
        }
    }
#pragma unroll
    for (int s = 0; s < 2; s++)
#pragma unroll
        for (int r = 0; r < 4; r++) {
            int node = mblk + s * 16 + kg * 4 + r;
            if (node < NNODES) {
#pragma unroll
                for (int n = 0; n < 8; n++)
                    S16[node * HID + n * 16 + r16] = f2bf(acc[s][n][r]);
            }
        }
}

// ---------------- graph boundaries ----------------
__global__ void bounds_kernel(const int* __restrict__ batch,
                              int* __restrict__ first, int* __restrict__ last) {
    int n = blockIdx.x * 256 + threadIdx.x;
    if (n >= NNODES) return;
    int g = batch[n];
    if (n == 0 || batch[n - 1] != g) first[g] = n;
    if (n == NNODES - 1 || batch[n + 1] != g) last[g] = n;
}

// ---------------- pool: relu(S + b2), segmented sums ----------------
__global__ void pool2(const ushort_t* __restrict__ S16, const float* __restrict__ b2,
                      const int* __restrict__ batch, float* __restrict__ sums) {
    int j = threadIdx.x;  // 0..127
    int n0 = blockIdx.x * 128;
    int nend = n0 + 128 < NNODES ? n0 + 128 : NNODES;
    float bb = b2[j];
    float acc = 0.0f;
    int gcur = batch[n0];
    for (int n = n0; n < nend; n++) {
        int g = batch[n];
        if (g != gcur) {
            atomicAdd(&sums[gcur * HID + j], acc);
            acc = 0.0f; gcur = g;
        }
        acc += fmaxf(bf2f(S16[n * HID + j]) + bb, 0.0f);
    }
    atomicAdd(&sums[gcur * HID + j], acc);
}

// ---------------- head ----------------
__global__ void head_kernel(const float* __restrict__ sums, const int* __restrict__ first,
                            const int* __restrict__ last,
                            const float* __restrict__ Wlin, const float* __restrict__ blin,
                            float* __restrict__ out) {
    int g = threadIdx.x;
    if (g >= NGRAPHS) return;
    int f = first[g];
    float cnt = (f >= 0) ? (float)(last[g] - f + 1) : 1.0f;
    float l0 = blin[0], l1 = blin[1];
    for (int i = 0; i < HID; i++) {
        float p = sums[g * HID + i] / cnt;
        l0 += p * Wlin[i * 2 + 0];
        l1 += p * Wlin[i * 2 + 1];
    }
    float m = fmaxf(l0, l1);
    float e0 = __expf(l0 - m), e1 = __expf(l1 - m);
    float s = e0 + e1;
    out[g * 2 + 0] = e0 / s;
    out[g * 2 + 1] = e1 / s;
}

// ---------------- workspace layout (4-byte units) ----------------
#define NPAD      100096                          // 782*128
#define OFF_DINV  0
#define OFF_DEGI  (OFF_DINV + NPAD)
#define OFF_OFF   (OFF_DEGI + NPAD)
#define OFF_BCNT  (OFF_OFF + NPAD)                // 783+pad
#define OFF_BBASE (OFF_BCNT + 800)
#define OFF_GC    (OFF_BBASE + 800)
#define OFF_ENT   (OFF_GC + 800)                  // uint[NEDGES]
#define OFF_SRC   (OFF_ENT + NEDGES)              // int[NEDGES]
#define OFF_P0    (OFF_SRC + NEDGES)
#define OFF_P1    (OFF_P0 + NNODES * HID / 2)     // bf16 [N,128] = N*64 words
#define OFF_P2    (OFF_P1 + NNODES * HID / 2)
#define OFF_P3    (OFF_P2 + NNODES * HID / 2)
#define OFF_S16   (OFF_P3 + NNODES * HID / 2)     // bf16 S; h1..h3 alias (dead before gemm4)
#define OFF_H1    OFF_S16
#define OFF_H2    (OFF_H1 + NNODES * 4)
#define OFF_H3    (OFF_H2 + NNODES * 4)
#define OFF_WT    (OFF_S16 + NNODES * HID / 2)
#define OFF_SUMS  (OFF_WT + 32768)
#define OFF_FIRST (OFF_SUMS + NGRAPHS * HID)
#define OFF_LAST  (OFF_FIRST + NGRAPHS)

extern "C" void kernel_launch(void* const* d_in, const int* in_sizes, int n_in,
                              void* d_out, int out_size, void* d_ws, size_t ws_size,
                              hipStream_t stream) {
    const float* x    = (const float*)d_in[0];
    const float* W1   = (const float*)d_in[1];
    const float* b1   = (const float*)d_in[2];
    const float* W2   = (const float*)d_in[3];
    const float* b2   = (const float*)d_in[4];
    const float* Wlin = (const float*)d_in[5];
    const float* blin = (const float*)d_in[6];
    const int* ei     = (const int*)d_in[7];
    const int* batch  = (const int*)d_in[8];
    float* out = (float*)d_out;

    const int* row = ei;
    const int* col = ei + NEDGES;

    float* ws = (float*)d_ws;
    float* dinv    = ws + OFF_DINV;
    int*   degi    = (int*)(ws + OFF_DEGI);
    int*   off     = (int*)(ws + OFF_OFF);
    int*   bcnt    = (int*)(ws + OFF_BCNT);
    int*   bbase   = (int*)(ws + OFF_BBASE);
    int*   gc      = (int*)(ws + OFF_GC);
    uint_t* ent    = (uint_t*)(ws + OFF_ENT);
    int*   csr_src = (int*)(ws + OFF_SRC);
    ushort_t* P0   = (ushort_t*)(ws + OFF_P0);
    ushort_t* P1   = (ushort_t*)(ws + OFF_P1);
    ushort_t* P2   = (ushort_t*)(ws + OFF_P2);
    ushort_t* P3   = (ushort_t*)(ws + OFF_P3);
    ushort_t* S16  = (ushort_t*)(ws + OFF_S16);
    float* h1      = ws + OFF_H1;
    float* h2      = ws + OFF_H2;
    float* h3      = ws + OFF_H3;
    ushort_t* Wt   = (ushort_t*)(ws + OFF_WT);
    float* sums    = ws + OFF_SUMS;
    int*   first   = (int*)(ws + OFF_FIRST);
    int*   last    = (int*)(ws + OFF_LAST);

    // ---- init ----
    hipMemsetAsync(bcnt, 0, 800 * sizeof(int), stream);
    hipMemsetAsync(sums, 0, NGRAPHS * HID * sizeof(float), stream);
    hipMemsetAsync(first, 0xFF, 2 * NGRAPHS * sizeof(int), stream);

    // ---- CSR build (bucket counting sort, no random global scatter) ----
    hist_k<<<NCHB, 256, 0, stream>>>(col, bcnt);
    bscan_k<<<1, 1024, 0, stream>>>(bcnt, bbase, gc);
    bfill_k<<<NCHB, 256, 0, stream>>>(row, col, gc, ent);
    sortb_k<<<NBKT, 256, 0, stream>>>(ent, bbase, csr_src, degi, off);
    dinv_kernel<<<(NNODES + 255) / 256, 256, 0, stream>>>(degi, dinv);
    wt_kernel<<<(512 * 128) / 256, 256, 0, stream>>>(W2, Wt);
    bounds_kernel<<<(NNODES + 255) / 256, 256, 0, stream>>>(batch, first, last);

    // ---- layer 1 (fp32, F=4) ----
    gprop4<<<(NNODES + 255) / 256, 256, 0, stream>>>(off, csr_src, dinv, x, h1);
    gprop4<<<(NNODES + 255) / 256, 256, 0, stream>>>(off, csr_src, dinv, h1, h2);
    gprop4<<<(NNODES + 255) / 256, 256, 0, stream>>>(off, csr_src, dinv, h2, h3);
    combine1<<<NNODES / 4, 128, 0, stream>>>(x, h1, h2, h3, W1, b1, P0);

    // ---- layer 2 hops (bf16) ----
    gprop128<<<(NNODES * 16) / 256, 256, 0, stream>>>(off, csr_src, dinv, P0, P1);
    gprop128<<<(NNODES * 16) / 256, 256, 0, stream>>>(off, csr_src, dinv, P1, P2);
    gprop128<<<(NNODES * 16) / 256, 256, 0, stream>>>(off, csr_src, dinv, P2, P3);

    // ---- fused MFMA combine (K=512) ----
    gemm4<<<(NNODES + 127) / 128, 256, 0, stream>>>(P0, P1, P2, P3, Wt, S16);

    // ---- pool + head ----
    pool2<<<(NNODES + 127) / 128, 128, 0, stream>>>(S16, b2, batch, sums);
    head_kernel<<<1, 128, 0, stream>>>(sums, first, last, Wlin, blin, out);
}

// Round 6
// 435.224 us; speedup vs baseline: 23.2168x; 1.0866x over previous
//
#include <hip/hip_runtime.h>

#define NNODES 100000
#define NEDGES 1600000
#define NGRAPHS 128
#define HID 128
#define NBKT 782            // ceil(100000/128)
#define CHUNK 8192
#define NCHB ((NEDGES + CHUNK - 1) / CHUNK)   // 196
#define MAXB 3072           // bucket edge cap (mean 2048, sigma ~45)

typedef unsigned short ushort_t;
typedef unsigned int uint_t;
typedef __attribute__((ext_vector_type(8))) short short8;
typedef __attribute__((ext_vector_type(4))) float floatx4;

__device__ __forceinline__ float bf2f(ushort_t u) {
    return __uint_as_float(((unsigned)u) << 16);
}
__device__ __forceinline__ ushort_t f2bf(float f) {
    unsigned u = __float_as_uint(f);
    return (ushort_t)((u + 0x7fffu + ((u >> 16) & 1u)) >> 16);
}

// ---------------- bucket histogram (LDS-staged) ----------------
__global__ void hist_k(const int* __restrict__ col, int* __restrict__ bcnt) {
    __shared__ int l[NBKT];
    for (int i = threadIdx.x; i < NBKT; i += 256) l[i] = 0;
    __syncthreads();
    int base = blockIdx.x * CHUNK;
    int lim = base + CHUNK < NEDGES ? base + CHUNK : NEDGES;
    for (int e = base + threadIdx.x; e < lim; e += 256)
        atomicAdd(&l[col[e] >> 7], 1);
    __syncthreads();
    for (int i = threadIdx.x; i < NBKT; i += 256)
        if (l[i]) atomicAdd(&bcnt[i], l[i]);
}

// ---------------- scan 782 buckets (single block) ----------------
__global__ void bscan_k(const int* __restrict__ bcnt, int* __restrict__ bbase,
                        int* __restrict__ gc) {
    __shared__ int l[1024];
    int t = threadIdx.x;
    int v0 = (t < NBKT) ? bcnt[t] : 0;
    l[t] = v0;
    __syncthreads();
    for (int d = 1; d < 1024; d <<= 1) {
        int v = (t >= d) ? l[t - d] : 0;
        __syncthreads();
        l[t] += v;
        __syncthreads();
    }
    if (t < NBKT) { int ex = l[t] - v0; bbase[t] = ex; gc[t] = ex; }
    if (t == 0) bbase[NBKT] = NEDGES;
}

// ---------------- bucket scatter: one range-claim atomic per (block,bucket) ----------------
__global__ void bfill_k(const int* __restrict__ row, const int* __restrict__ col,
                        int* __restrict__ gc, uint_t* __restrict__ entry) {
    __shared__ int lcnt[NBKT], lbase[NBKT];
    for (int i = threadIdx.x; i < NBKT; i += 256) lcnt[i] = 0;
    __syncthreads();
    int base = blockIdx.x * CHUNK;
    int lim = base + CHUNK < NEDGES ? base + CHUNK : NEDGES;
    for (int e = base + threadIdx.x; e < lim; e += 256)
        atomicAdd(&lcnt[col[e] >> 7], 1);
    __syncthreads();
    for (int i = threadIdx.x; i < NBKT; i += 256) {
        int c = lcnt[i];
        lbase[i] = c ? atomicAdd(&gc[i], c) : 0;
        lcnt[i] = 0;   // reuse as fill cursor
    }
    __syncthreads();
    for (int e = base + threadIdx.x; e < lim; e += 256) {
        int c = col[e];
        int b = c >> 7;
        int pos = lbase[b] + atomicAdd(&lcnt[b], 1);
        entry[pos] = (uint_t)row[e] | ((uint_t)(c & 127) << 17);
    }
}

// ---------------- per-bucket LDS counting sort -> csr_src, degi, off ----------------
__global__ void sortb_k(const uint_t* __restrict__ entry, const int* __restrict__ bbase,
                        int* __restrict__ csr_src, int* __restrict__ degi,
                        int* __restrict__ off) {
    __shared__ uint_t ents[MAXB];
    __shared__ uint_t sorted[MAXB];
    __shared__ int ncnt[128], nsc[128], nfill[128];
    int b = blockIdx.x;
    int base = bbase[b];
    int cnt = bbase[b + 1] - base;
    if (cnt > MAXB) cnt = MAXB;
    int t = threadIdx.x;
    if (t < 128) { ncnt[t] = 0; nfill[t] = 0; }
    __syncthreads();
    for (int i = t; i < cnt; i += 256) {
        uint_t v = entry[base + i];
        ents[i] = v;
        atomicAdd(&ncnt[v >> 17], 1);
    }
    __syncthreads();
    if (t < 128) nsc[t] = ncnt[t];
    __syncthreads();
    for (int d = 1; d < 128; d <<= 1) {
        int v = (t >= d && t < 128) ? nsc[t - d] : 0;
        __syncthreads();
        if (t < 128) nsc[t] += v;   // inclusive scan
        __syncthreads();
    }
    if (t < 128) {
        int n = b * 128 + t;
        if (n < NNODES) { degi[n] = ncnt[t]; off[n] = base + nsc[t]; }
        nsc[t] -= ncnt[t];          // exclusive
    }
    __syncthreads();
    for (int i = t; i < cnt; i += 256) {
        uint_t v = ents[i];
        int dl = v >> 17;
        int pos = nsc[dl] + atomicAdd(&nfill[dl], 1);
        sorted[pos] = v & 0x1FFFFu;
    }
    __syncthreads();
    for (int i = t; i < cnt; i += 256) csr_src[base + i] = (int)sorted[i];
}

__global__ void dinv_kernel(const int* __restrict__ degi, float* __restrict__ dinv) {
    int i = blockIdx.x * blockDim.x + threadIdx.x;
    if (i < NNODES) {
        int d = degi[i];
        dinv[i] = (d > 0) ? rsqrtf((float)d) : 0.0f;
    }
}

// ---------------- layer-1 gather (F=4, fp32), unroll 4 ----------------
__global__ void gprop4(const int* __restrict__ off, const int* __restrict__ csr_src,
                       const float* __restrict__ dinv,
                       const float* __restrict__ hin, float* __restrict__ hout) {
    int n = blockIdx.x * 256 + threadIdx.x;
    if (n >= NNODES) return;
    int k = n ? off[n - 1] : 0;
    int end = off[n];
    float dn = dinv[n];
    float4 acc = {0.f, 0.f, 0.f, 0.f};
    for (; k + 3 < end; k += 4) {
        int s0 = csr_src[k], s1 = csr_src[k + 1], s2 = csr_src[k + 2], s3 = csr_src[k + 3];
        float w0 = dinv[s0] * dn, w1 = dinv[s1] * dn, w2 = dinv[s2] * dn, w3 = dinv[s3] * dn;
        float4 v0 = *(const float4*)(hin + s0 * 4);
        float4 v1 = *(const float4*)(hin + s1 * 4);
        float4 v2 = *(const float4*)(hin + s2 * 4);
        float4 v3 = *(const float4*)(hin + s3 * 4);
        acc.x += w0 * v0.x + w1 * v1.x + w2 * v2.x + w3 * v3.x;
        acc.y += w0 * v0.y + w1 * v1.y + w2 * v2.y + w3 * v3.y;
        acc.z += w0 * v0.z + w1 * v1.z + w2 * v2.z + w3 * v3.z;
        acc.w += w0 * v0.w + w1 * v1.w + w2 * v2.w + w3 * v3.w;
    }
    for (; k < end; k++) {
        int s = csr_src[k];
        float w = dinv[s] * dn;
        float4 v = *(const float4*)(hin + s * 4);
        acc.x += w * v.x; acc.y += w * v.y; acc.z += w * v.z; acc.w += w * v.w;
    }
    *(float4*)(hout + n * 4) = acc;
}

// ---------------- layer-2 gather helper: acc8 += wgt * bf16x8(v) ----------------
__device__ __forceinline__ void acc8(float* a, float wgt, uint4 v) {
    a[0] += wgt * __uint_as_float(v.x << 16);
    a[1] += wgt * __uint_as_float(v.x & 0xffff0000u);
    a[2] += wgt * __uint_as_float(v.y << 16);
    a[3] += wgt * __uint_as_float(v.y & 0xffff0000u);
    a[4] += wgt * __uint_as_float(v.z << 16);
    a[5] += wgt * __uint_as_float(v.z & 0xffff0000u);
    a[6] += wgt * __uint_as_float(v.w << 16);
    a[7] += wgt * __uint_as_float(v.w & 0xffff0000u);
}

// ---------------- layer-2 gather (F=128 bf16), 16 lanes/node, unroll 4 ----------------
__global__ void gprop128(const int* __restrict__ off, const int* __restrict__ csr_src,
                         const float* __restrict__ dinv,
                         const ushort_t* __restrict__ hin, ushort_t* __restrict__ hout) {
    int t = blockIdx.x * 256 + threadIdx.x;
    int n = t >> 4, lane = t & 15;
    if (n >= NNODES) return;
    int k = n ? off[n - 1] : 0;
    int end = off[n];
    float dn = dinv[n];
    int fo = lane * 8;
    float a[8] = {0.f, 0.f, 0.f, 0.f, 0.f, 0.f, 0.f, 0.f};
    for (; k + 3 < end; k += 4) {
        int s0 = csr_src[k], s1 = csr_src[k + 1], s2 = csr_src[k + 2], s3 = csr_src[k + 3];
        float w0 = dinv[s0] * dn, w1 = dinv[s1] * dn, w2 = dinv[s2] * dn, w3 = dinv[s3] * dn;
        uint4 v0 = *(const uint4*)(hin + s0 * HID + fo);
        uint4 v1 = *(const uint4*)(hin + s1 * HID + fo);
        uint4 v2 = *(const uint4*)(hin + s2 * HID + fo);
        uint4 v3 = *(const uint4*)(hin + s3 * HID + fo);
        acc8(a, w0, v0); acc8(a, w1, v1); acc8(a, w2, v2); acc8(a, w3, v3);
    }
    for (; k < end; k++) {
        int s = csr_src[k];
        float w = dinv[s] * dn;
        uint4 v = *(const uint4*)(hin + s * HID + fo);
        acc8(a, w, v);
    }
    uint4 o;
    o.x = (unsigned)f2bf(a[0]) | ((unsigned)f2bf(a[1]) << 16);
    o.y = (unsigned)f2bf(a[2]) | ((unsigned)f2bf(a[3]) << 16);
    o.z = (unsigned)f2bf(a[4]) | ((unsigned)f2bf(a[5]) << 16);
    o.w = (unsigned)f2bf(a[6]) | ((unsigned)f2bf(a[7]) << 16);
    *(uint4*)(hout + n * HID + fo) = o;
}

// ---------------- layer-1 combine -> bf16 P0 ----------------
__global__ void combine1(const float* __restrict__ x, const float* __restrict__ h1,
                         const float* __restrict__ h2, const float* __restrict__ h3,
                         const float* __restrict__ W1, const float* __restrict__ b1,
                         ushort_t* __restrict__ P0) {
    __shared__ float hs[4][16];
    int n0 = blockIdx.x * 4;
    int j = threadIdx.x;  // 0..127
    if (j < 64) {
        int n = j >> 4, v = j & 15, k = v >> 2, i = v & 3;
        const float* src = (k == 0) ? x : (k == 1) ? h1 : (k == 2) ? h2 : h3;
        hs[n][v] = src[(n0 + n) * 4 + i];
    }
    __syncthreads();
    float w[16];
#pragma unroll
    for (int v = 0; v < 16; v++) w[v] = W1[v * 128 + j];
    float bb = b1[j];
#pragma unroll
    for (int n = 0; n < 4; n++) {
        float acc = bb;
#pragma unroll
        for (int v = 0; v < 16; v++) acc += hs[n][v] * w[v];
        P0[(n0 + n) * 128 + j] = f2bf(fmaxf(acc, 0.0f));
    }
}

// ---------------- W2 transpose to bf16: Wt[j][k] (k = hop*128+i) ----------------
__global__ void wt_kernel(const float* __restrict__ W2, ushort_t* __restrict__ Wt) {
    int t = blockIdx.x * 256 + threadIdx.x;
    if (t >= 512 * 128) return;
    int j = t >> 9, k = t & 511;
    Wt[t] = f2bf(W2[k * 128 + j]);
}

// ---------------- fused MFMA + pool: sums[g] += relu(sum_hop P_hop@W2[hop] + b2) ----------------
// 16-node tile per wave (6250 tiles), 4 waves/block. No S16 materialization.
__global__ __launch_bounds__(256) void gemm4p(
    const ushort_t* __restrict__ P0, const ushort_t* __restrict__ P1,
    const ushort_t* __restrict__ P2, const ushort_t* __restrict__ P3,
    const ushort_t* __restrict__ Wt, const float* __restrict__ b2,
    const int* __restrict__ batch, float* __restrict__ sums) {
    int tid = threadIdx.x;
    int w = tid >> 6, lane = tid & 63;
    int r16 = lane & 15, kg = lane >> 4;
    int tb = (blockIdx.x * 4 + w) * 16;   // tile base node
    if (tb >= NNODES) return;             // 100000 % 16 == 0: tiles never partial
    int node0 = tb + r16;
    floatx4 acc[8];
#pragma unroll
    for (int n = 0; n < 8; n++) acc[n] = (floatx4){0.f, 0.f, 0.f, 0.f};
    const ushort_t* Ps[4] = {P0, P1, P2, P3};
#pragma unroll
    for (int hop = 0; hop < 4; hop++) {
        const ushort_t* P = Ps[hop];
#pragma unroll
        for (int k0 = 0; k0 < 128; k0 += 32) {
            int f = k0 + kg * 8;
            short8 a = *(const short8*)(P + node0 * HID + f);
            int kk = hop * 128 + f;
#pragma unroll
            for (int n = 0; n < 8; n++) {
                short8 b = *(const short8*)(Wt + (n * 16 + r16) * 512 + kk);
                acc[n] = __builtin_amdgcn_mfma_f32_16x16x32_bf16(a, b, acc[n], 0, 0, 0);
            }
        }
    }
    // C/D layout: col = n*16 + r16, row = kg*4 + r  (node = tb + row)
    float bb[8];
#pragma unroll
    for (int n = 0; n < 8; n++) bb[n] = b2[n * 16 + r16];
    int g0 = batch[tb], g15 = batch[tb + 15];
    if (g0 == g15) {
        // fast path: whole tile in one graph -> cross-kg shfl reduce, 8 atomics on kg==0 lanes
#pragma unroll
        for (int n = 0; n < 8; n++) {
            float s = fmaxf(acc[n][0] + bb[n], 0.0f) + fmaxf(acc[n][1] + bb[n], 0.0f) +
                      fmaxf(acc[n][2] + bb[n], 0.0f) + fmaxf(acc[n][3] + bb[n], 0.0f);
            s += __shfl_xor(s, 16);
            s += __shfl_xor(s, 32);
            if (kg == 0) atomicAdd(&sums[g0 * HID + n * 16 + r16], s);
        }
    } else {
        // boundary tile (~127 of 6250): per-row atomics
#pragma unroll
        for (int r = 0; r < 4; r++) {
            int g = batch[tb + kg * 4 + r];
#pragma unroll
            for (int n = 0; n < 8; n++)
                atomicAdd(&sums[g * HID + n * 16 + r16], fmaxf(acc[n][r] + bb[n], 0.0f));
        }
    }
}

// ---------------- graph boundaries ----------------
__global__ void bounds_kernel(const int* __restrict__ batch,
                              int* __restrict__ first, int* __restrict__ last) {
    int n = blockIdx.x * 256 + threadIdx.x;
    if (n >= NNODES) return;
    int g = batch[n];
    if (n == 0 || batch[n - 1] != g) first[g] = n;
    if (n == NNODES - 1 || batch[n + 1] != g) last[g] = n;
}

// ---------------- head ----------------
__global__ void head_kernel(const float* __restrict__ sums, const int* __restrict__ first,
                            const int* __restrict__ last,
                            const float* __restrict__ Wlin, const float* __restrict__ blin,
                            float* __restrict__ out) {
    int g = threadIdx.x;
    if (g >= NGRAPHS) return;
    int f = first[g];
    float cnt = (f >= 0) ? (float)(last[g] - f + 1) : 1.0f;
    float l0 = blin[0], l1 = blin[1];
    for (int i = 0; i < HID; i++) {
        float p = sums[g * HID + i] / cnt;
        l0 += p * Wlin[i * 2 + 0];
        l1 += p * Wlin[i * 2 + 1];
    }
    float m = fmaxf(l0, l1);
    float e0 = __expf(l0 - m), e1 = __expf(l1 - m);
    float s = e0 + e1;
    out[g * 2 + 0] = e0 / s;
    out[g * 2 + 1] = e1 / s;
}

// ---------------- workspace layout (4-byte units) ----------------
#define NPAD      100096                          // 782*128
#define OFF_DINV  0
#define OFF_DEGI  (OFF_DINV + NPAD)
#define OFF_OFF   (OFF_DEGI + NPAD)
#define OFF_BCNT  (OFF_OFF + NPAD)
#define OFF_BBASE (OFF_BCNT + 800)
#define OFF_GC    (OFF_BBASE + 800)
#define OFF_ENT   (OFF_GC + 800)                  // uint[NEDGES]
#define OFF_SRC   (OFF_ENT + NEDGES)              // int[NEDGES]
#define OFF_P0    (OFF_SRC + NEDGES)
#define OFF_P1    (OFF_P0 + NNODES * HID / 2)     // bf16 [N,128] = N*64 words
#define OFF_P2    (OFF_P1 + NNODES * HID / 2)
#define OFF_P3    (OFF_P2 + NNODES * HID / 2)
#define OFF_H1    (OFF_P3 + NNODES * HID / 2)
#define OFF_H2    (OFF_H1 + NNODES * 4)
#define OFF_H3    (OFF_H2 + NNODES * 4)
#define OFF_WT    (OFF_H3 + NNODES * 4)
#define OFF_SUMS  (OFF_WT + 32768)
#define OFF_FIRST (OFF_SUMS + NGRAPHS * HID)
#define OFF_LAST  (OFF_FIRST + NGRAPHS)

extern "C" void kernel_launch(void* const* d_in, const int* in_sizes, int n_in,
                              void* d_out, int out_size, void* d_ws, size_t ws_size,
                              hipStream_t stream) {
    const float* x    = (const float*)d_in[0];
    const float* W1   = (const float*)d_in[1];
    const float* b1   = (const float*)d_in[2];
    const float* W2   = (const float*)d_in[3];
    const float* b2   = (const float*)d_in[4];
    const float* Wlin = (const float*)d_in[5];
    const float* blin = (const float*)d_in[6];
    const int* ei     = (const int*)d_in[7];
    const int* batch  = (const int*)d_in[8];
    float* out = (float*)d_out;

    const int* row = ei;
    const int* col = ei + NEDGES;

    float* ws = (float*)d_ws;
    float* dinv    = ws + OFF_DINV;
    int*   degi    = (int*)(ws + OFF_DEGI);
    int*   off     = (int*)(ws + OFF_OFF);
    int*   bcnt    = (int*)(ws + OFF_BCNT);
    int*   bbase   = (int*)(ws + OFF_BBASE);
    int*   gc      = (int*)(ws + OFF_GC);
    uint_t* ent    = (uint_t*)(ws + OFF_ENT);
    int*   csr_src = (int*)(ws + OFF_SRC);
    ushort_t* P0   = (ushort_t*)(ws + OFF_P0);
    ushort_t* P1   = (ushort_t*)(ws + OFF_P1);
    ushort_t* P2   = (ushort_t*)(ws + OFF_P2);
    ushort_t* P3   = (ushort_t*)(ws + OFF_P3);
    float* h1      = ws + OFF_H1;
    float* h2      = ws + OFF_H2;
    float* h3      = ws + OFF_H3;
    ushort_t* Wt   = (ushort_t*)(ws + OFF_WT);
    float* sums    = ws + OFF_SUMS;
    int*   first   = (int*)(ws + OFF_FIRST);
    int*   last    = (int*)(ws + OFF_LAST);

    // ---- init ----
    hipMemsetAsync(bcnt, 0, 800 * sizeof(int), stream);
    hipMemsetAsync(sums, 0, NGRAPHS * HID * sizeof(float), stream);
    hipMemsetAsync(first, 0xFF, 2 * NGRAPHS * sizeof(int), stream);

    // ---- CSR build (bucket counting sort) ----
    hist_k<<<NCHB, 256, 0, stream>>>(col, bcnt);
    bscan_k<<<1, 1024, 0, stream>>>(bcnt, bbase, gc);
    bfill_k<<<NCHB, 256, 0, stream>>>(row, col, gc, ent);
    sortb_k<<<NBKT, 256, 0, stream>>>(ent, bbase, csr_src, degi, off);
    dinv_kernel<<<(NNODES + 255) / 256, 256, 0, stream>>>(degi, dinv);
    wt_kernel<<<(512 * 128) / 256, 256, 0, stream>>>(W2, Wt);
    bounds_kernel<<<(NNODES + 255) / 256, 256, 0, stream>>>(batch, first, last);

    // ---- layer 1 (fp32, F=4) ----
    gprop4<<<(NNODES + 255) / 256, 256, 0, stream>>>(off, csr_src, dinv, x, h1);
    gprop4<<<(NNODES + 255) / 256, 256, 0, stream>>>(off, csr_src, dinv, h1, h2);
    gprop4<<<(NNODES + 255) / 256, 256, 0, stream>>>(off, csr_src, dinv, h2, h3);
    combine1<<<NNODES / 4, 128, 0, stream>>>(x, h1, h2, h3, W1, b1, P0);

    // ---- layer 2 hops (bf16) ----
    gprop128<<<(NNODES * 16) / 256, 256, 0, stream>>>(off, csr_src, dinv, P0, P1);
    gprop128<<<(NNODES * 16) / 256, 256, 0, stream>>>(off, csr_src, dinv, P1, P2);
    gprop128<<<(NNODES * 16) / 256, 256, 0, stream>>>(off, csr_src, dinv, P2, P3);

    // ---- fused MFMA combine + pool (K=512, 16-node wave tiles) ----
    gemm4p<<<(NNODES / 16 + 3) / 4, 256, 0, stream>>>(P0, P1, P2, P3, Wt, b2, batch, sums);

    // ---- head ----
    head_kernel<<<1, 128, 0, stream>>>(sums, first, last, Wlin, blin, out);
}

// Round 7
// 360.101 us; speedup vs baseline: 28.0601x; 1.2086x over previous
//
#include <hip/hip_runtime.h>

#define NNODES 100000
#define NEDGES 1600000
#define NGRAPHS 128
#define HID 128
#define NBKT 782            // ceil(100000/128)
#define CHUNK 8192
#define NCHB ((NEDGES + CHUNK - 1) / CHUNK)   // 196
#define MAXB 3072           // bucket edge cap (mean 2048, sigma ~45)

typedef unsigned short ushort_t;
typedef unsigned int uint_t;
typedef __attribute__((ext_vector_type(8))) short short8;
typedef __attribute__((ext_vector_type(4))) float floatx4;

__device__ __forceinline__ float bf2f(ushort_t u) {
    return __uint_as_float(((unsigned)u) << 16);
}
__device__ __forceinline__ ushort_t f2bf(float f) {
    unsigned u = __float_as_uint(f);
    return (ushort_t)((u + 0x7fffu + ((u >> 16) & 1u)) >> 16);
}

// ---------------- bucket histogram (LDS-staged) ----------------
__global__ void hist_k(const int* __restrict__ col, int* __restrict__ bcnt) {
    __shared__ int l[NBKT];
    for (int i = threadIdx.x; i < NBKT; i += 256) l[i] = 0;
    __syncthreads();
    int base = blockIdx.x * CHUNK;
    int lim = base + CHUNK < NEDGES ? base + CHUNK : NEDGES;
    for (int e = base + threadIdx.x; e < lim; e += 256)
        atomicAdd(&l[col[e] >> 7], 1);
    __syncthreads();
    for (int i = threadIdx.x; i < NBKT; i += 256)
        if (l[i]) atomicAdd(&bcnt[i], l[i]);
}

// ---------------- scan 782 buckets (single block) ----------------
__global__ void bscan_k(const int* __restrict__ bcnt, int* __restrict__ bbase,
                        int* __restrict__ gc) {
    __shared__ int l[1024];
    int t = threadIdx.x;
    int v0 = (t < NBKT) ? bcnt[t] : 0;
    l[t] = v0;
    __syncthreads();
    for (int d = 1; d < 1024; d <<= 1) {
        int v = (t >= d) ? l[t - d] : 0;
        __syncthreads();
        l[t] += v;
        __syncthreads();
    }
    if (t < NBKT) { int ex = l[t] - v0; bbase[t] = ex; gc[t] = ex; }
    if (t == 0) bbase[NBKT] = NEDGES;
}

// ---------------- bucket scatter: one range-claim atomic per (block,bucket) ----------------
__global__ void bfill_k(const int* __restrict__ row, const int* __restrict__ col,
                        int* __restrict__ gc, uint_t* __restrict__ entry) {
    __shared__ int lcnt[NBKT], lbase[NBKT];
    for (int i = threadIdx.x; i < NBKT; i += 256) lcnt[i] = 0;
    __syncthreads();
    int base = blockIdx.x * CHUNK;
    int lim = base + CHUNK < NEDGES ? base + CHUNK : NEDGES;
    for (int e = base + threadIdx.x; e < lim; e += 256)
        atomicAdd(&lcnt[col[e] >> 7], 1);
    __syncthreads();
    for (int i = threadIdx.x; i < NBKT; i += 256) {
        int c = lcnt[i];
        lbase[i] = c ? atomicAdd(&gc[i], c) : 0;
        lcnt[i] = 0;   // reuse as fill cursor
    }
    __syncthreads();
    for (int e = base + threadIdx.x; e < lim; e += 256) {
        int c = col[e];
        int b = c >> 7;
        int pos = lbase[b] + atomicAdd(&lcnt[b], 1);
        entry[pos] = (uint_t)row[e] | ((uint_t)(c & 127) << 17);
    }
}

// ---------------- per-bucket LDS counting sort -> csr_src, degi, off ----------------
__global__ void sortb_k(const uint_t* __restrict__ entry, const int* __restrict__ bbase,
                        int* __restrict__ csr_src, int* __restrict__ degi,
                        int* __restrict__ off) {
    __shared__ uint_t ents[MAXB];
    __shared__ uint_t sorted[MAXB];
    __shared__ int ncnt[128], nsc[128], nfill[128];
    int b = blockIdx.x;
    int base = bbase[b];
    int cnt = bbase[b + 1] - base;
    if (cnt > MAXB) cnt = MAXB;
    int t = threadIdx.x;
    if (t < 128) { ncnt[t] = 0; nfill[t] = 0; }
    __syncthreads();
    for (int i = t; i < cnt; i += 256) {
        uint_t v = entry[base + i];
        ents[i] = v;
        atomicAdd(&ncnt[v >> 17], 1);
    }
    __syncthreads();
    if (t < 128) nsc[t] = ncnt[t];
    __syncthreads();
    for (int d = 1; d < 128; d <<= 1) {
        int v = (t >= d && t < 128) ? nsc[t - d] : 0;
        __syncthreads();
        if (t < 128) nsc[t] += v;   // inclusive scan
        __syncthreads();
    }
    if (t < 128) {
        int n = b * 128 + t;
        if (n < NNODES) { degi[n] = ncnt[t]; off[n] = base + nsc[t]; }
        nsc[t] -= ncnt[t];          // exclusive
    }
    __syncthreads();
    for (int i = t; i < cnt; i += 256) {
        uint_t v = ents[i];
        int dl = v >> 17;
        int pos = nsc[dl] + atomicAdd(&nfill[dl], 1);
        sorted[pos] = v & 0x1FFFFu;
    }
    __syncthreads();
    for (int i = t; i < cnt; i += 256) csr_src[base + i] = (int)sorted[i];
}

__global__ void dinv_kernel(const int* __restrict__ degi, float* __restrict__ dinv) {
    int i = blockIdx.x * blockDim.x + threadIdx.x;
    if (i < NNODES) {
        int d = degi[i];
        dinv[i] = (d > 0) ? rsqrtf((float)d) : 0.0f;
    }
}

// ---------------- layer-1 gather (F=4, fp32), unroll 4 ----------------
__global__ void gprop4(const int* __restrict__ off, const int* __restrict__ csr_src,
                       const float* __restrict__ dinv,
                       const float* __restrict__ hin, float* __restrict__ hout) {
    int n = blockIdx.x * 256 + threadIdx.x;
    if (n >= NNODES) return;
    int k = n ? off[n - 1] : 0;
    int end = off[n];
    float dn = dinv[n];
    float4 acc = {0.f, 0.f, 0.f, 0.f};
    for (; k + 3 < end; k += 4) {
        int s0 = csr_src[k], s1 = csr_src[k + 1], s2 = csr_src[k + 2], s3 = csr_src[k + 3];
        float w0 = dinv[s0] * dn, w1 = dinv[s1] * dn, w2 = dinv[s2] * dn, w3 = dinv[s3] * dn;
        float4 v0 = *(const float4*)(hin + s0 * 4);
        float4 v1 = *(const float4*)(hin + s1 * 4);
        float4 v2 = *(const float4*)(hin + s2 * 4);
        float4 v3 = *(const float4*)(hin + s3 * 4);
        acc.x += w0 * v0.x + w1 * v1.x + w2 * v2.x + w3 * v3.x;
        acc.y += w0 * v0.y + w1 * v1.y + w2 * v2.y + w3 * v3.y;
        acc.z += w0 * v0.z + w1 * v1.z + w2 * v2.z + w3 * v3.z;
        acc.w += w0 * v0.w + w1 * v1.w + w2 * v2.w + w3 * v3.w;
    }
    for (; k < end; k++) {
        int s = csr_src[k];
        float w = dinv[s] * dn;
        float4 v = *(const float4*)(hin + s * 4);
        acc.x += w * v.x; acc.y += w * v.y; acc.z += w * v.z; acc.w += w * v.w;
    }
    *(float4*)(hout + n * 4) = acc;
}

// ---------------- layer-2 gather helper: acc8 += wgt * bf16x8(v) ----------------
__device__ __forceinline__ void acc8(float* a, float wgt, uint4 v) {
    a[0] += wgt * __uint_as_float(v.x << 16);
    a[1] += wgt * __uint_as_float(v.x & 0xffff0000u);
    a[2] += wgt * __uint_as_float(v.y << 16);
    a[3] += wgt * __uint_as_float(v.y & 0xffff0000u);
    a[4] += wgt * __uint_as_float(v.z << 16);
    a[5] += wgt * __uint_as_float(v.z & 0xffff0000u);
    a[6] += wgt * __uint_as_float(v.w << 16);
    a[7] += wgt * __uint_as_float(v.w & 0xffff0000u);
}

// ---------------- layer-2 gather (F=128 bf16), 16 lanes/node, unroll 4 ----------------
__global__ void gprop128(const int* __restrict__ off, const int* __restrict__ csr_src,
                         const float* __restrict__ dinv,
                         const ushort_t* __restrict__ hin, ushort_t* __restrict__ hout) {
    int t = blockIdx.x * 256 + threadIdx.x;
    int n = t >> 4, lane = t & 15;
    if (n >= NNODES) return;
    int k = n ? off[n - 1] : 0;
    int end = off[n];
    float dn = dinv[n];
    int fo = lane * 8;
    float a[8] = {0.f, 0.f, 0.f, 0.f, 0.f, 0.f, 0.f, 0.f};
    for (; k + 3 < end; k += 4) {
        int s0 = csr_src[k], s1 = csr_src[k + 1], s2 = csr_src[k + 2], s3 = csr_src[k + 3];
        float w0 = dinv[s0] * dn, w1 = dinv[s1] * dn, w2 = dinv[s2] * dn, w3 = dinv[s3] * dn;
        uint4 v0 = *(const uint4*)(hin + s0 * HID + fo);
        uint4 v1 = *(const uint4*)(hin + s1 * HID + fo);
        uint4 v2 = *(const uint4*)(hin + s2 * HID + fo);
        uint4 v3 = *(const uint4*)(hin + s3 * HID + fo);
        acc8(a, w0, v0); acc8(a, w1, v1); acc8(a, w2, v2); acc8(a, w3, v3);
    }
    for (; k < end; k++) {
        int s = csr_src[k];
        float w = dinv[s] * dn;
        uint4 v = *(const uint4*)(hin + s * HID + fo);
        acc8(a, w, v);
    }
    uint4 o;
    o.x = (unsigned)f2bf(a[0]) | ((unsigned)f2bf(a[1]) << 16);
    o.y = (unsigned)f2bf(a[2]) | ((unsigned)f2bf(a[3]) << 16);
    o.z = (unsigned)f2bf(a[4]) | ((unsigned)f2bf(a[5]) << 16);
    o.w = (unsigned)f2bf(a[6]) | ((unsigned)f2bf(a[7]) << 16);
    *(uint4*)(hout + n * HID + fo) = o;
}

// ---------------- layer-1 combine -> bf16 P0 ----------------
__global__ void combine1(const float* __restrict__ x, const float* __restrict__ h1,
                         const float* __restrict__ h2, const float* __restrict__ h3,
                         const float* __restrict__ W1, const float* __restrict__ b1,
                         ushort_t* __restrict__ P0) {
    __shared__ float hs[4][16];
    int n0 = blockIdx.x * 4;
    int j = threadIdx.x;  // 0..127
    if (j < 64) {
        int n = j >> 4, v = j & 15, k = v >> 2, i = v & 3;
        const float* src = (k == 0) ? x : (k == 1) ? h1 : (k == 2) ? h2 : h3;
        hs[n][v] = src[(n0 + n) * 4 + i];
    }
    __syncthreads();
    float w[16];
#pragma unroll
    for (int v = 0; v < 16; v++) w[v] = W1[v * 128 + j];
    float bb = b1[j];
#pragma unroll
    for (int n = 0; n < 4; n++) {
        float acc = bb;
#pragma unroll
        for (int v = 0; v < 16; v++) acc += hs[n][v] * w[v];
        P0[(n0 + n) * 128 + j] = f2bf(fmaxf(acc, 0.0f));
    }
}

// ---------------- W2 transpose to bf16: Wt[j][k] (k = hop*128+i) ----------------
__global__ void wt_kernel(const float* __restrict__ W2, ushort_t* __restrict__ Wt) {
    int t = blockIdx.x * 256 + threadIdx.x;
    if (t >= 512 * 128) return;
    int j = t >> 9, k = t & 511;
    Wt[t] = f2bf(W2[k * 128 + j]);
}

// ---------------- fused MFMA + pool, B staged in LDS ----------------
// Block = 128 nodes (4 waves x 32-node tiles). Wt (128KB) staged in 2 stages of 64KB
// (2 hops each), XOR-swizzled: byte_in_row ^= (row&7)<<4 -> stride-512B reads conflict-free.
__global__ __launch_bounds__(256) void gemm4p(
    const ushort_t* __restrict__ P0, const ushort_t* __restrict__ P1,
    const ushort_t* __restrict__ P2, const ushort_t* __restrict__ P3,
    const ushort_t* __restrict__ Wt, const float* __restrict__ b2,
    const int* __restrict__ batch, float* __restrict__ sums) {
    __shared__ ushort_t Bs[32768];   // 64 KB: 128 rows x 512 B (2 hops worth of K)
    int tid = threadIdx.x;
    int w = tid >> 6, lane = tid & 63;
    int r16 = lane & 15, kg = lane >> 4;
    int tb = blockIdx.x * 128 + w * 32;   // wave tile base node; 100000 % 32 == 0
    bool active = (tb < NNODES);
    floatx4 acc[2][8];
#pragma unroll
    for (int s = 0; s < 2; s++)
#pragma unroll
        for (int n = 0; n < 8; n++) acc[s][n] = (floatx4){0.f, 0.f, 0.f, 0.f};
    const ushort_t* Ps[4] = {P0, P1, P2, P3};
    for (int stage = 0; stage < 2; stage++) {
        __syncthreads();   // protect LDS reuse across stages
        // stage 64 KB: rows 0..127, 32 x 16B slots per row, swizzled
#pragma unroll
        for (int i = 0; i < 16; i++) {
            int idx = i * 256 + tid;          // 16B-unit index, 4096 total
            int r = idx >> 5;                 // row 0..127
            int slot = idx & 31;
            int cb = (slot * 16) ^ ((r & 7) << 4);
            *(uint4*)((char*)Bs + r * 512 + cb) =
                *(const uint4*)(Wt + r * 512 + stage * 256 + slot * 8);
        }
        __syncthreads();
        if (active) {
#pragma unroll
            for (int hh = 0; hh < 2; hh++) {
                const ushort_t* P = Ps[stage * 2 + hh];
#pragma unroll
                for (int k0 = 0; k0 < 128; k0 += 32) {
                    int f = k0 + kg * 8;
                    short8 a0 = *(const short8*)(P + (tb + r16) * HID + f);
                    short8 a1 = *(const short8*)(P + (tb + 16 + r16) * HID + f);
#pragma unroll
                    for (int n = 0; n < 8; n++) {
                        int r = n * 16 + r16;
                        int cb = (hh * 256 + k0 * 2 + kg * 16) ^ ((r & 7) << 4);
                        short8 b = *(const short8*)((const char*)Bs + r * 512 + cb);
                        acc[0][n] = __builtin_amdgcn_mfma_f32_16x16x32_bf16(a0, b, acc[0][n], 0, 0, 0);
                        acc[1][n] = __builtin_amdgcn_mfma_f32_16x16x32_bf16(a1, b, acc[1][n], 0, 0, 0);
                    }
                }
            }
        }
    }
    if (!active) return;
    // C/D layout: col = n*16 + r16, row(within subtile s) = kg*4 + r; node = tb + s*16 + kg*4 + r
    float bb[8];
#pragma unroll
    for (int n = 0; n < 8; n++) bb[n] = b2[n * 16 + r16];
    int g0 = batch[tb], g31 = batch[tb + 31];
    if (g0 == g31) {
        // fast path: whole 32-node tile in one graph
#pragma unroll
        for (int n = 0; n < 8; n++) {
            float s = 0.0f;
#pragma unroll
            for (int st = 0; st < 2; st++)
#pragma unroll
                for (int r = 0; r < 4; r++) s += fmaxf(acc[st][n][r] + bb[n], 0.0f);
            s += __shfl_xor(s, 16);
            s += __shfl_xor(s, 32);
            if (kg == 0) atomicAdd(&sums[g0 * HID + n * 16 + r16], s);
        }
    } else {
        // boundary tile: per-row atomics
#pragma unroll
        for (int st = 0; st < 2; st++)
#pragma unroll
            for (int r = 0; r < 4; r++) {
                int g = batch[tb + st * 16 + kg * 4 + r];
#pragma unroll
                for (int n = 0; n < 8; n++)
                    atomicAdd(&sums[g * HID + n * 16 + r16], fmaxf(acc[st][n][r] + bb[n], 0.0f));
            }
    }
}

// ---------------- graph boundaries ----------------
__global__ void bounds_kernel(const int* __restrict__ batch,
                              int* __restrict__ first, int* __restrict__ last) {
    int n = blockIdx.x * 256 + threadIdx.x;
    if (n >= NNODES) return;
    int g = batch[n];
    if (n == 0 || batch[n - 1] != g) first[g] = n;
    if (n == NNODES - 1 || batch[n + 1] != g) last[g] = n;
}

// ---------------- head ----------------
__global__ void head_kernel(const float* __restrict__ sums, const int* __restrict__ first,
                            const int* __restrict__ last,
                            const float* __restrict__ Wlin, const float* __restrict__ blin,
                            float* __restrict__ out) {
    int g = threadIdx.x;
    if (g >= NGRAPHS) return;
    int f = first[g];
    float cnt = (f >= 0) ? (float)(last[g] - f + 1) : 1.0f;
    float l0 = blin[0], l1 = blin[1];
    for (int i = 0; i < HID; i++) {
        float p = sums[g * HID + i] / cnt;
        l0 += p * Wlin[i * 2 + 0];
        l1 += p * Wlin[i * 2 + 1];
    }
    float m = fmaxf(l0, l1);
    float e0 = __expf(l0 - m), e1 = __expf(l1 - m);
    float s = e0 + e1;
    out[g * 2 + 0] = e0 / s;
    out[g * 2 + 1] = e1 / s;
}

// ---------------- workspace layout (4-byte units) ----------------
#define NPAD      100096                          // 782*128
#define OFF_DINV  0
#define OFF_DEGI  (OFF_DINV + NPAD)
#define OFF_OFF   (OFF_DEGI + NPAD)
#define OFF_BCNT  (OFF_OFF + NPAD)
#define OFF_BBASE (OFF_BCNT + 800)
#define OFF_GC    (OFF_BBASE + 800)
#define OFF_ENT   (OFF_GC + 800)                  // uint[NEDGES]
#define OFF_SRC   (OFF_ENT + NEDGES)              // int[NEDGES]
#define OFF_P0    (OFF_SRC + NEDGES)
#define OFF_P1    (OFF_P0 + NNODES * HID / 2)     // bf16 [N,128] = N*64 words
#define OFF_P2    (OFF_P1 + NNODES * HID / 2)
#define OFF_P3    (OFF_P2 + NNODES * HID / 2)
#define OFF_H1    (OFF_P3 + NNODES * HID / 2)
#define OFF_H2    (OFF_H1 + NNODES * 4)
#define OFF_H3    (OFF_H2 + NNODES * 4)
#define OFF_WT    (OFF_H3 + NNODES * 4)
#define OFF_SUMS  (OFF_WT + 32768)
#define OFF_FIRST (OFF_SUMS + NGRAPHS * HID)
#define OFF_LAST  (OFF_FIRST + NGRAPHS)

extern "C" void kernel_launch(void* const* d_in, const int* in_sizes, int n_in,
                              void* d_out, int out_size, void* d_ws, size_t ws_size,
                              hipStream_t stream) {
    const float* x    = (const float*)d_in[0];
    const float* W1   = (const float*)d_in[1];
    const float* b1   = (const float*)d_in[2];
    const float* W2   = (const float*)d_in[3];
    const float* b2   = (const float*)d_in[4];
    const float* Wlin = (const float*)d_in[5];
    const float* blin = (const float*)d_in[6];
    const int* ei     = (const int*)d_in[7];
    const int* batch  = (const int*)d_in[8];
    float* out = (float*)d_out;

    const int* row = ei;
    const int* col = ei + NEDGES;

    float* ws = (float*)d_ws;
    float* dinv    = ws + OFF_DINV;
    int*   degi    = (int*)(ws + OFF_DEGI);
    int*   off     = (int*)(ws + OFF_OFF);
    int*   bcnt    = (int*)(ws + OFF_BCNT);
    int*   bbase   = (int*)(ws + OFF_BBASE);
    int*   gc      = (int*)(ws + OFF_GC);
    uint_t* ent    = (uint_t*)(ws + OFF_ENT);
    int*   csr_src = (int*)(ws + OFF_SRC);
    ushort_t* P0   = (ushort_t*)(ws + OFF_P0);
    ushort_t* P1   = (ushort_t*)(ws + OFF_P1);
    ushort_t* P2   = (ushort_t*)(ws + OFF_P2);
    ushort_t* P3   = (ushort_t*)(ws + OFF_P3);
    float* h1      = ws + OFF_H1;
    float* h2      = ws + OFF_H2;
    float* h3      = ws + OFF_H3;
    ushort_t* Wt   = (ushort_t*)(ws + OFF_WT);
    float* sums    = ws + OFF_SUMS;
    int*   first   = (int*)(ws + OFF_FIRST);
    int*   last    = (int*)(ws + OFF_LAST);

    // ---- init ----
    hipMemsetAsync(bcnt, 0, 800 * sizeof(int), stream);
    hipMemsetAsync(sums, 0, NGRAPHS * HID * sizeof(float), stream);
    hipMemsetAsync(first, 0xFF, 2 * NGRAPHS * sizeof(int), stream);

    // ---- CSR build (bucket counting sort) ----
    hist_k<<<NCHB, 256, 0, stream>>>(col, bcnt);
    bscan_k<<<1, 1024, 0, stream>>>(bcnt, bbase, gc);
    bfill_k<<<NCHB, 256, 0, stream>>>(row, col, gc, ent);
    sortb_k<<<NBKT, 256, 0, stream>>>(ent, bbase, csr_src, degi, off);
    dinv_kernel<<<(NNODES + 255) / 256, 256, 0, stream>>>(degi, dinv);
    wt_kernel<<<(512 * 128) / 256, 256, 0, stream>>>(W2, Wt);
    bounds_kernel<<<(NNODES + 255) / 256, 256, 0, stream>>>(batch, first, last);

    // ---- layer 1 (fp32, F=4) ----
    gprop4<<<(NNODES + 255) / 256, 256, 0, stream>>>(off, csr_src, dinv, x, h1);
    gprop4<<<(NNODES + 255) / 256, 256, 0, stream>>>(off, csr_src, dinv, h1, h2);
    gprop4<<<(NNODES + 255) / 256, 256, 0, stream>>>(off, csr_src, dinv, h2, h3);
    combine1<<<NNODES / 4, 128, 0, stream>>>(x, h1, h2, h3, W1, b1, P0);

    // ---- layer 2 hops (bf16) ----
    gprop128<<<(NNODES * 16) / 256, 256, 0, stream>>>(off, csr_src, dinv, P0, P1);
    gprop128<<<(NNODES * 16) / 256, 256, 0, stream>>>(off, csr_src, dinv, P1, P2);
    gprop128<<<(NNODES * 16) / 256, 256, 0, stream>>>(off, csr_src, dinv, P2, P3);

    // ---- fused MFMA combine + pool (K=512, B in LDS) ----
    gemm4p<<<(NNODES + 127) / 128, 256, 0, stream>>>(P0, P1, P2, P3, Wt, b2, batch, sums);

    // ---- head ----
    head_kernel<<<1, 128, 0, stream>>>(sums, first, last, Wlin, blin, out);
}